// Round 1
// baseline (25625.018 us; speedup 1.0000x reference)
//
#include <hip/hip_runtime.h>
#include <math.h>

// Problem constants (fixed by reference setup_inputs)
constexpr int D = 768;    // model dim
constexpr int E = 8;      // experts
constexpr int F = 3072;   // ffn dim
constexpr int T = 8192;   // tokens = B*S = 4*2048
constexpr float EPS = 1e-6f;

// ---------------------------------------------------------------------------
// Kernel 1: router logits + softmax/top-2 + RMS stats + expert list build.
// One wave (64 lanes) per token; 4 waves per block.
// ---------------------------------------------------------------------------
__global__ __launch_bounds__(256)
void router_norm_kernel(const float* __restrict__ x,
                        const float* __restrict__ rw,      // [E, D]
                        float* __restrict__ out,           // [T, D] <- wsum * x
                        float* __restrict__ logits,        // [T, E]
                        float* __restrict__ rstd,          // [T]
                        int*   __restrict__ counts,        // [E]
                        int*   __restrict__ lists,         // [E, T]
                        float* __restrict__ wlist)         // [E, T]
{
    const int lane = threadIdx.x & 63;
    const int wid  = threadIdx.x >> 6;
    const int t = blockIdx.x * 4 + wid;
    if (t >= T) return;

    const float* xr = x + (size_t)t * D;
    float xv[12];
    float acc[8];
#pragma unroll
    for (int e = 0; e < 8; ++e) acc[e] = 0.f;
    float ssq = 0.f;
#pragma unroll
    for (int i = 0; i < 12; ++i) {
        const int k = lane + 64 * i;
        const float v = xr[k];
        xv[i] = v;
        ssq += v * v;
#pragma unroll
        for (int e = 0; e < 8; ++e) acc[e] += v * rw[e * D + k];
    }
    // butterfly reduce across the 64-lane wave: every lane ends with full sums
#pragma unroll
    for (int off = 32; off; off >>= 1) {
        ssq += __shfl_xor(ssq, off);
#pragma unroll
        for (int e = 0; e < 8; ++e) acc[e] += __shfl_xor(acc[e], off);
    }

    // top-2 of logits (softmax is monotone; ties -> lowest index, matching top_k)
    int e0 = 0; float m0 = acc[0];
#pragma unroll
    for (int e = 1; e < 8; ++e) if (acc[e] > m0) { m0 = acc[e]; e0 = e; }
    int e1 = -1; float m1 = -3.4e38f;
#pragma unroll
    for (int e = 0; e < 8; ++e) if (e != e0 && acc[e] > m1) { m1 = acc[e]; e1 = e; }

    // renormalized top-2 weights: softmax denominator cancels exactly
    const float r  = expf(m1 - m0);
    const float w0 = 1.f / (1.f + r);
    const float w1 = r * w0;
    const float wsum = w0 + w1;

    if (lane == 0) {
#pragma unroll
        for (int e = 0; e < 8; ++e) logits[t * 8 + e] = acc[e];
        rstd[t] = rsqrtf(ssq * (1.f / (float)D) + EPS);
        int p0 = atomicAdd(&counts[e0], 1);
        lists[e0 * T + p0] = t; wlist[e0 * T + p0] = w0;
        int p1 = atomicAdd(&counts[e1], 1);
        lists[e1 * T + p1] = t; wlist[e1 * T + p1] = w1;
    }

    // out = (w0+w1) * x   (FFN contributions atomically added later)
#pragma unroll
    for (int i = 0; i < 12; ++i) {
        const int k = lane + 64 * i;
        out[(size_t)t * D + k] = wsum * xv[i];
    }
}

// ---------------------------------------------------------------------------
// Kernel 2: fused FFN per expert.  grid = (T/16, E).  16 tokens per block.
// Stage token rows (LN-scaled, RMS-normalized) in LDS; loop F in tiles of 16:
//   stage1: each thread computes one h[tt][ft] = <x_row, wi_row> ; relu -> LDS
//   stage2: each thread owns 3 output columns x 16 tokens, accumulates
//           against contiguous wo[d][f0..f0+15].
// Output: atomicAdd of w_token * acc into out (2 adds/element total -> commutative).
// ---------------------------------------------------------------------------
__global__ __launch_bounds__(256)
void moe_ffn_kernel(const float* __restrict__ x,
                    const float* __restrict__ rstd,
                    const float* __restrict__ ln_w,     // [E, D]
                    const float* __restrict__ wi,       // [E, F, D]
                    const float* __restrict__ wo,       // [E, D, F]
                    const int*   __restrict__ counts,
                    const int*   __restrict__ lists,
                    const float* __restrict__ wlist,
                    float* __restrict__ out)
{
    const int e = blockIdx.y;
    const int cnt = counts[e];
    const int base = blockIdx.x * 16;
    if (base >= cnt) return;
    const int nt = min(16, cnt - base);

    __shared__ float s_x[16][772];   // +4 float pad: rows land on distinct banks
    __shared__ float sh[16][16];
    __shared__ int   s_tok[16];
    __shared__ float s_w[16];

    const int tid = threadIdx.x;
    if (tid < 16) {
        if (tid < nt) {
            s_tok[tid] = lists[e * T + base + tid];
            s_w[tid]   = wlist[e * T + base + tid];
        } else {
            s_tok[tid] = -1;
            s_w[tid]   = 0.f;
        }
    }
    __syncthreads();

    // stage token rows into LDS: x * rstd * ln_w[e]
    for (int rrow = 0; rrow < 16; ++rrow) {
        const int tok = s_tok[rrow];
        const float rs = (tok >= 0) ? rstd[tok] : 0.f;
        const float* src = x + (size_t)(tok >= 0 ? tok : 0) * D;
#pragma unroll
        for (int j = 0; j < 3; ++j) {
            const int c = tid + 256 * j;
            s_x[rrow][c] = (tok >= 0) ? src[c] * rs * ln_w[e * D + c] : 0.f;
        }
    }
    __syncthreads();

    float acc0[16], acc1[16], acc2[16];
#pragma unroll
    for (int t = 0; t < 16; ++t) { acc0[t] = 0.f; acc1[t] = 0.f; acc2[t] = 0.f; }

    const int tt = tid >> 4;    // token within tile
    const int ft = tid & 15;    // f within f-tile

    for (int f0 = 0; f0 < F; f0 += 16) {
        // ---- stage 1: h = <s_x[tt][:], wi[e][f0+ft][:]> -------------------
        const float4* wr  = (const float4*)(wi + ((size_t)e * F + f0 + ft) * D);
        const float4* xr4 = (const float4*)(&s_x[tt][0]);
        float h = 0.f;
#pragma unroll 8
        for (int k = 0; k < 192; ++k) {
            const float4 a = xr4[k];
            const float4 b = wr[k];
            h += a.x * b.x + a.y * b.y + a.z * b.z + a.w * b.w;
        }
        __syncthreads();              // prior stage-2 readers of sh are done
        sh[tt][ft] = fmaxf(h, 0.f);
        __syncthreads();

        // ---- stage 2: acc[t][d] += sum_ft sh[t][ft] * wo[e][d][f0+ft] -----
#pragma unroll
        for (int j = 0; j < 3; ++j) {
            const int d = tid + 256 * j;
            const float4* wv4 = (const float4*)(wo + ((size_t)e * D + d) * F + f0);
            const float4 W0 = wv4[0], W1 = wv4[1], W2 = wv4[2], W3 = wv4[3];
#pragma unroll
            for (int t = 0; t < 16; ++t) {
                const float4* s4 = (const float4*)(&sh[t][0]);
                const float4 A = s4[0], B = s4[1], C = s4[2], Dd = s4[3];
                float p = A.x * W0.x + A.y * W0.y + A.z * W0.z + A.w * W0.w
                        + B.x * W1.x + B.y * W1.y + B.z * W1.z + B.w * W1.w
                        + C.x * W2.x + C.y * W2.y + C.z * W2.z + C.w * W2.w
                        + Dd.x * W3.x + Dd.y * W3.y + Dd.z * W3.z + Dd.w * W3.w;
                if (j == 0) acc0[t] += p;
                else if (j == 1) acc1[t] += p;
                else acc2[t] += p;
            }
        }
    }

    // scatter-add weighted contributions (token unique within this expert)
#pragma unroll
    for (int t = 0; t < 16; ++t) {
        if (t < nt) {
            const int tok = s_tok[t];
            const float w = s_w[t];
            float* dst = out + (size_t)tok * D;
            atomicAdd(&dst[tid],       w * acc0[t]);
            atomicAdd(&dst[tid + 256], w * acc1[t]);
            atomicAdd(&dst[tid + 512], w * acc2[t]);
        }
    }
}

// ---------------------------------------------------------------------------
extern "C" void kernel_launch(void* const* d_in, const int* in_sizes, int n_in,
                              void* d_out, int out_size, void* d_ws, size_t ws_size,
                              hipStream_t stream) {
    const float* x   = (const float*)d_in[0];   // [T, D]
    const float* rw  = (const float*)d_in[1];   // [E, D]
    const float* lnw = (const float*)d_in[2];   // [E, D]
    const float* wi  = (const float*)d_in[3];   // [E, F, D]
    const float* wo  = (const float*)d_in[4];   // [E, D, F]
    // d_in[5] = top_k (fixed = 2, hardcoded)

    float* out    = (float*)d_out;                       // [T, D]
    float* logits = (float*)d_out + (size_t)T * D;       // [T, E]

    // workspace layout (all fully rewritten each call)
    char* ws = (char*)d_ws;
    int*   counts = (int*)ws;                            // [E]      @ 0
    int*   lists  = (int*)(ws + 256);                    // [E*T]    @ 256
    float* wlist  = (float*)(ws + 256 + (size_t)E * T * 4);
    float* rstd   = (float*)(ws + 256 + 2 * (size_t)E * T * 4);

    hipMemsetAsync(counts, 0, E * sizeof(int), stream);

    router_norm_kernel<<<T / 4, 256, 0, stream>>>(x, rw, out, logits, rstd,
                                                  counts, lists, wlist);

    dim3 grid(T / 16, E);
    moe_ffn_kernel<<<grid, 256, 0, stream>>>(x, rstd, lnw, wi, wo,
                                             counts, lists, wlist, out);
}

// Round 2
// 818.823 us; speedup vs baseline: 31.2949x; 31.2949x over previous
//
#include <hip/hip_runtime.h>
#include <hip/hip_bf16.h>
#include <math.h>

typedef short short8 __attribute__((ext_vector_type(8)));
typedef float f32x16 __attribute__((ext_vector_type(16)));

constexpr int D = 768;    // model dim
constexpr int E = 8;      // experts
constexpr int F = 3072;   // ffn dim
constexpr int T = 8192;   // tokens = 4*2048
constexpr float EPS = 1e-6f;

static __device__ inline unsigned short f2bf(float f) {
    __hip_bfloat16 h = __float2bfloat16(f);
    return *reinterpret_cast<unsigned short*>(&h);
}

static __device__ inline f32x16 mfma_bf16(short8 a, short8 b, f32x16 c) {
    return __builtin_amdgcn_mfma_f32_32x32x16_bf16(a, b, c, 0, 0, 0);
}

// ---------------------------------------------------------------------------
// Weight conversion: wi' = bf16(wi * ln_w) (ln_w folded), wo' = bf16(wo).
// ---------------------------------------------------------------------------
__global__ __launch_bounds__(256)
void convert_weights(const float* __restrict__ wi, const float* __restrict__ wo,
                     const float* __restrict__ lnw,
                     unsigned short* __restrict__ wip, unsigned short* __restrict__ wop)
{
    const long long NWI = (long long)E * F * D;
    long long i4 = ((long long)blockIdx.x * 256 + threadIdx.x) * 4;
    if (i4 < NWI) {
        float4 v = *(const float4*)(wi + i4);
        int e = (int)(i4 / ((long long)F * D));
        int d = (int)(i4 % D);
        float4 l = *(const float4*)(lnw + e * D + d);
        ushort4 o = { f2bf(v.x * l.x), f2bf(v.y * l.y), f2bf(v.z * l.z), f2bf(v.w * l.w) };
        *(ushort4*)(wip + i4) = o;
    } else {
        long long j = i4 - NWI;
        float4 v = *(const float4*)(wo + j);
        ushort4 o = { f2bf(v.x), f2bf(v.y), f2bf(v.z), f2bf(v.w) };
        *(ushort4*)(wop + j) = o;
    }
}

// ---------------------------------------------------------------------------
// Router + RMS-norm: logits (exact fp32), top-2 weights, xn = bf16(x*rstd),
// packed expert lists (token<<1 | slot), wsum per token.
// One 64-lane wave per token.
// ---------------------------------------------------------------------------
__global__ __launch_bounds__(256)
void router_norm_kernel(const float* __restrict__ x,
                        const float* __restrict__ rw,
                        float* __restrict__ logits,        // [T, E]
                        unsigned short* __restrict__ xn,   // [T, D] bf16
                        float* __restrict__ wsum,          // [T]
                        int*   __restrict__ counts,        // [E]
                        int*   __restrict__ lists,         // [E, T] packed
                        float* __restrict__ wlist)         // [E, T]
{
    const int lane = threadIdx.x & 63;
    const int wid  = threadIdx.x >> 6;
    const int t = blockIdx.x * 4 + wid;
    if (t >= T) return;

    const float* xr = x + (size_t)t * D;
    float xv[12];
    float acc[8];
#pragma unroll
    for (int e = 0; e < 8; ++e) acc[e] = 0.f;
    float ssq = 0.f;
#pragma unroll
    for (int i = 0; i < 12; ++i) {
        const int k = lane + 64 * i;
        const float v = xr[k];
        xv[i] = v;
        ssq += v * v;
#pragma unroll
        for (int e = 0; e < 8; ++e) acc[e] += v * rw[e * D + k];
    }
#pragma unroll
    for (int off = 32; off; off >>= 1) {
        ssq += __shfl_xor(ssq, off);
#pragma unroll
        for (int e = 0; e < 8; ++e) acc[e] += __shfl_xor(acc[e], off);
    }

    int e0 = 0; float m0 = acc[0];
#pragma unroll
    for (int e = 1; e < 8; ++e) if (acc[e] > m0) { m0 = acc[e]; e0 = e; }
    int e1 = -1; float m1 = -3.4e38f;
#pragma unroll
    for (int e = 0; e < 8; ++e) if (e != e0 && acc[e] > m1) { m1 = acc[e]; e1 = e; }

    const float r  = expf(m1 - m0);
    const float w0 = 1.f / (1.f + r);
    const float w1 = r * w0;

    const float rs = rsqrtf(ssq * (1.f / (float)D) + EPS);

    if (lane == 0) {
#pragma unroll
        for (int e = 0; e < 8; ++e) logits[t * 8 + e] = acc[e];
        wsum[t] = w0 + w1;
        int p0 = atomicAdd(&counts[e0], 1);
        lists[e0 * T + p0] = (t << 1) | 0; wlist[e0 * T + p0] = w0;
        int p1 = atomicAdd(&counts[e1], 1);
        lists[e1 * T + p1] = (t << 1) | 1; wlist[e1 * T + p1] = w1;
    }

    // xn = bf16(x * rstd); consecutive lanes -> consecutive k (coalesced)
#pragma unroll
    for (int i = 0; i < 12; ++i) {
        const int k = lane + 64 * i;
        xn[(size_t)t * D + k] = f2bf(xv[i] * rs);
    }
}

// ---------------------------------------------------------------------------
// Fused FFN, bf16 MFMA. Block = 64 tokens of one expert, full D output.
// 8 waves (512 thr). Chunks of BF=256 over F:
//   phase1: Hc[64][256] = s_x @ wi'^T   (wave w -> N-frag w; 2 M-frags each)
//   phase2: Otile[64][768] += relu(Hc) @ wo'^T (wave w -> cols w*96..+96)
// s_x [64][768]bf16 + s_h [64][256]bf16 in LDS, XOR-swizzle (row&15)<<4.
// Non-atomic weighted scatter to ffout[slot][tok][d].
// ---------------------------------------------------------------------------
__global__ __launch_bounds__(512, 2)
void ffn_kernel(const unsigned short* __restrict__ xn,
                const unsigned short* __restrict__ wip,
                const unsigned short* __restrict__ wop,
                const int* __restrict__ counts,
                const int* __restrict__ lists,
                const float* __restrict__ wlist,
                float* __restrict__ ffout)
{
    extern __shared__ char smem[];
    const int bid = blockIdx.x;
    const int e = bid & 7;                 // expert == XCD (id%8 round-robin)
    const int base = (bid >> 3) * 64;
    const int cnt = counts[e];
    if (base >= cnt) return;
    const int nt = min(64, cnt - base);
    const int tid = threadIdx.x;
    const int lane = tid & 63;
    const int w = tid >> 6;
    const int lo = lane & 31;
    const int hi = lane >> 5;

    int*   s_tok = (int*)(smem + 131072);
    float* s_wgt = (float*)(smem + 131328);
    if (tid < 64) {
        if (tid < nt) {
            s_tok[tid] = lists[e * T + base + tid];
            s_wgt[tid] = wlist[e * T + base + tid];
        } else { s_tok[tid] = 0; s_wgt[tid] = 0.f; }
    }
    __syncthreads();

    // ---- stage s_x: row = tid>>3, 8 threads/row, 12x 16B chunks each ----
    {
        const int row = tid >> 3, c8 = tid & 7;
        const int sw = (row & 15) << 4;
        if (row < nt) {
            const unsigned short* src = xn + (size_t)(s_tok[row] >> 1) * D + c8 * 96;
#pragma unroll
            for (int j = 0; j < 12; ++j) {
                uint4 v = *(const uint4*)(src + j * 8);
                *(uint4*)(smem + ((row * 1536 + (c8 * 96 + j * 8) * 2) ^ sw)) = v;
            }
        } else {
            const uint4 z = make_uint4(0, 0, 0, 0);
#pragma unroll
            for (int j = 0; j < 12; ++j)
                *(uint4*)(smem + ((row * 1536 + (c8 * 96 + j * 8) * 2) ^ sw)) = z;
        }
    }
    __syncthreads();

    f32x16 oacc[2][3];
#pragma unroll
    for (int mf = 0; mf < 2; ++mf)
#pragma unroll
        for (int j = 0; j < 3; ++j)
#pragma unroll
            for (int q = 0; q < 16; ++q) oacc[mf][j][q] = 0.f;

    const unsigned short* wie = wip + (size_t)e * F * D;
    const unsigned short* woe = wop + (size_t)e * D * F;

    const int axor = (lo & 15) << 4;              // same for row lo and lo+32
    const int a0 = lo * 1536 + hi * 16;           // s_x byte base, M-frag 0
    const int a1 = (32 + lo) * 1536 + hi * 16;    // M-frag 1
    const int h0b = 98304 + lo * 512 + hi * 16;   // s_h byte bases
    const int h1b = 98304 + (32 + lo) * 512 + hi * 16;

    const unsigned short* wo0 = woe + (size_t)((w * 3 + 0) * 32 + lo) * F + hi * 8;
    const unsigned short* wo1 = woe + (size_t)((w * 3 + 1) * 32 + lo) * F + hi * 8;
    const unsigned short* wo2 = woe + (size_t)((w * 3 + 2) * 32 + lo) * F + hi * 8;

    for (int c = 0; c < 12; ++c) {
        const int f0 = c * 256;
        // ---------- phase 1 ----------
        f32x16 hA, hB;
#pragma unroll
        for (int q = 0; q < 16; ++q) { hA[q] = 0.f; hB[q] = 0.f; }
        const unsigned short* bp = wie + (size_t)(f0 + w * 32 + lo) * D + hi * 8;
#pragma unroll 4
        for (int ks = 0; ks < 48; ++ks) {
            short8 b  = *(const short8*)(bp + ks * 16);
            short8 aA = *(const short8*)(smem + ((a0 + ks * 32) ^ axor));
            short8 aB = *(const short8*)(smem + ((a1 + ks * 32) ^ axor));
            hA = mfma_bf16(aA, b, hA);
            hB = mfma_bf16(aB, b, hB);
        }
        __syncthreads();   // prior phase-2 readers of s_h done
        {
            const int col2 = (w * 32 + lo) * 2;
#pragma unroll
            for (int r = 0; r < 16; ++r) {
                const int row = (r & 3) + 8 * (r >> 2) + 4 * hi;
                const int byteA = (98304 + row * 512 + col2) ^ ((row & 15) << 4);
                *(unsigned short*)(smem + byteA) = f2bf(fmaxf(hA[r], 0.f));
                const int rowB = row + 32;
                const int byteB = (98304 + rowB * 512 + col2) ^ ((rowB & 15) << 4);
                *(unsigned short*)(smem + byteB) = f2bf(fmaxf(hB[r], 0.f));
            }
        }
        __syncthreads();
        // ---------- phase 2 ----------
#pragma unroll 2
        for (int ks = 0; ks < 16; ++ks) {
            short8 aA = *(const short8*)(smem + ((h0b + ks * 32) ^ axor));
            short8 aB = *(const short8*)(smem + ((h1b + ks * 32) ^ axor));
            short8 b0 = *(const short8*)(wo0 + f0 + ks * 16);
            short8 b1 = *(const short8*)(wo1 + f0 + ks * 16);
            short8 b2 = *(const short8*)(wo2 + f0 + ks * 16);
            oacc[0][0] = mfma_bf16(aA, b0, oacc[0][0]);
            oacc[1][0] = mfma_bf16(aB, b0, oacc[1][0]);
            oacc[0][1] = mfma_bf16(aA, b1, oacc[0][1]);
            oacc[1][1] = mfma_bf16(aB, b1, oacc[1][1]);
            oacc[0][2] = mfma_bf16(aA, b2, oacc[0][2]);
            oacc[1][2] = mfma_bf16(aB, b2, oacc[1][2]);
        }
    }

    // ---------- epilogue: ffout[slot][tok][d] = w * acc (non-atomic) ----------
#pragma unroll
    for (int mf = 0; mf < 2; ++mf) {
#pragma unroll
        for (int r = 0; r < 16; ++r) {
            const int trow = mf * 32 + (r & 3) + 8 * (r >> 2) + 4 * hi;
            if (trow < nt) {
                const int pk = s_tok[trow];
                const float wt = s_wgt[trow];
                float* dst = ffout + ((size_t)(pk & 1) * T + (pk >> 1)) * D;
#pragma unroll
                for (int j = 0; j < 3; ++j)
                    dst[(w * 3 + j) * 32 + lo] = wt * oacc[mf][j][r];
            }
        }
    }
}

// ---------------------------------------------------------------------------
// Combine: out = wsum*x + ffout[0] + ffout[1]   (residual x stays fp32-exact)
// ---------------------------------------------------------------------------
__global__ __launch_bounds__(256)
void combine_kernel(const float* __restrict__ x, const float* __restrict__ wsum,
                    const float* __restrict__ ffout, float* __restrict__ out)
{
    const long long i4 = ((long long)blockIdx.x * 256 + threadIdx.x) * 4;
    const int t = (int)(i4 / D);
    float4 xv = *(const float4*)(x + i4);
    float4 f0 = *(const float4*)(ffout + i4);
    float4 f1 = *(const float4*)(ffout + (long long)T * D + i4);
    const float ws = wsum[t];
    float4 o = { ws * xv.x + f0.x + f1.x, ws * xv.y + f0.y + f1.y,
                 ws * xv.z + f0.z + f1.z, ws * xv.w + f0.w + f1.w };
    *(float4*)(out + i4) = o;
}

// ---------------------------------------------------------------------------
extern "C" void kernel_launch(void* const* d_in, const int* in_sizes, int n_in,
                              void* d_out, int out_size, void* d_ws, size_t ws_size,
                              hipStream_t stream) {
    const float* x   = (const float*)d_in[0];   // [T, D]
    const float* rw  = (const float*)d_in[1];   // [E, D]
    const float* lnw = (const float*)d_in[2];   // [E, D]
    const float* wi  = (const float*)d_in[3];   // [E, F, D]
    const float* wo  = (const float*)d_in[4];   // [E, D, F]

    float* out    = (float*)d_out;                    // [T, D]
    float* logits = (float*)d_out + (size_t)T * D;    // [T, E]

    char* ws = (char*)d_ws;
    int*            counts = (int*)(ws + 0);
    int*            lists  = (int*)(ws + 1024);                       // 8*8192*4
    float*          wlist  = (float*)(ws + 263168);
    float*          wsum   = (float*)(ws + 525312);
    unsigned short* xn     = (unsigned short*)(ws + 1048576);         // 12.0 MB
    unsigned short* wip    = (unsigned short*)(ws + 13631488);        // 36 MB
    unsigned short* wop    = (unsigned short*)(ws + 51380224);        // 36 MB
    float*          ffout  = (float*)(ws + 89128960);                 // 48 MB

    hipMemsetAsync(counts, 0, E * sizeof(int), stream);

    // weight conversion: (2*E*F*D)/4 elems / 256 threads
    convert_weights<<<36864, 256, 0, stream>>>(wi, wo, lnw, wip, wop);

    router_norm_kernel<<<T / 4, 256, 0, stream>>>(x, rw, logits, xn, wsum,
                                                  counts, lists, wlist);

    // 128 M-tiles (covers worst-case 8192 tokens on one expert) x 8 experts,
    // expert = blockIdx & 7 so each XCD's L2 serves one expert's weights.
    ffn_kernel<<<1024, 512, 131584, stream>>>(xn, wip, wop, counts, lists,
                                              wlist, ffout);

    combine_kernel<<<T * D / 4 / 256, 256, 0, stream>>>(x, wsum, ffout, out);
}

// Round 3
// 664.811 us; speedup vs baseline: 38.5448x; 1.2317x over previous
//
#include <hip/hip_runtime.h>
#include <hip/hip_bf16.h>
#include <math.h>

typedef short short8 __attribute__((ext_vector_type(8)));
typedef float f32x16 __attribute__((ext_vector_type(16)));

constexpr int D = 768;    // model dim
constexpr int E = 8;      // experts
constexpr int F = 3072;   // ffn dim
constexpr int FH = 1536;  // F half
constexpr int T = 8192;   // tokens
constexpr float EPS = 1e-6f;

static __device__ inline unsigned short f2bf(float f) {
    __hip_bfloat16 h = __float2bfloat16(f);
    return *reinterpret_cast<unsigned short*>(&h);
}

static __device__ inline f32x16 mfma_bf16(short8 a, short8 b, f32x16 c) {
    return __builtin_amdgcn_mfma_f32_32x32x16_bf16(a, b, c, 0, 0, 0);
}

// async global->LDS, 16B per lane; LDS dest = wave-uniform base + lane*16
#define GLL16(g, s) __builtin_amdgcn_global_load_lds( \
    (const __attribute__((address_space(1))) unsigned int*)(g), \
    (__attribute__((address_space(3))) unsigned int*)(s), 16, 0, 0)

// ---------------------------------------------------------------------------
// Weight conversion: wi' = bf16(wi * ln_w) (ln_w folded), wo' = bf16(wo).
// ---------------------------------------------------------------------------
__global__ __launch_bounds__(256)
void convert_weights(const float* __restrict__ wi, const float* __restrict__ wo,
                     const float* __restrict__ lnw,
                     unsigned short* __restrict__ wip, unsigned short* __restrict__ wop)
{
    const unsigned NWI = (unsigned)E * F * D;
    unsigned i4 = (blockIdx.x * 256u + threadIdx.x) * 4u;
    if (i4 < NWI) {
        float4 v = *(const float4*)(wi + i4);
        unsigned e = i4 / (unsigned)(F * D);
        unsigned d = i4 % (unsigned)D;
        float4 l = *(const float4*)(lnw + e * D + d);
        ushort4 o = { f2bf(v.x * l.x), f2bf(v.y * l.y), f2bf(v.z * l.z), f2bf(v.w * l.w) };
        *(ushort4*)(wip + i4) = o;
    } else {
        unsigned j = i4 - NWI;
        float4 v = *(const float4*)(wo + j);
        ushort4 o = { f2bf(v.x), f2bf(v.y), f2bf(v.z), f2bf(v.w) };
        *(ushort4*)(wop + j) = o;
    }
}

// ---------------------------------------------------------------------------
// Router + RMS-norm: logits (exact fp32), top-2, xn = bf16(x*rstd),
// out = wsum*x (residual term), packed expert lists (t<<1|slot).
// One 64-lane wave per token.
// ---------------------------------------------------------------------------
__global__ __launch_bounds__(256)
void router_norm_kernel(const float* __restrict__ x,
                        const float* __restrict__ rw,
                        float* __restrict__ logits,        // [T, E]
                        unsigned short* __restrict__ xn,   // [T, D] bf16
                        float* __restrict__ out,           // [T, D] <- wsum*x
                        int*   __restrict__ counts,        // [E]
                        int*   __restrict__ lists,         // [E, T] packed
                        float* __restrict__ wlist)         // [E, T]
{
    const int lane = threadIdx.x & 63;
    const int wid  = threadIdx.x >> 6;
    const int t = blockIdx.x * 4 + wid;
    if (t >= T) return;

    const float* xr = x + (size_t)t * D;
    float xv[12];
    float acc[8];
#pragma unroll
    for (int e = 0; e < 8; ++e) acc[e] = 0.f;
    float ssq = 0.f;
#pragma unroll
    for (int i = 0; i < 12; ++i) {
        const int k = lane + 64 * i;
        const float v = xr[k];
        xv[i] = v;
        ssq += v * v;
#pragma unroll
        for (int e = 0; e < 8; ++e) acc[e] += v * rw[e * D + k];
    }
#pragma unroll
    for (int off = 32; off; off >>= 1) {
        ssq += __shfl_xor(ssq, off);
#pragma unroll
        for (int e = 0; e < 8; ++e) acc[e] += __shfl_xor(acc[e], off);
    }

    int e0 = 0; float m0 = acc[0];
#pragma unroll
    for (int e = 1; e < 8; ++e) if (acc[e] > m0) { m0 = acc[e]; e0 = e; }
    int e1 = -1; float m1 = -3.4e38f;
#pragma unroll
    for (int e = 0; e < 8; ++e) if (e != e0 && acc[e] > m1) { m1 = acc[e]; e1 = e; }

    const float r  = expf(m1 - m0);
    const float w0 = 1.f / (1.f + r);
    const float w1 = r * w0;
    const float wsum = w0 + w1;
    const float rs = rsqrtf(ssq * (1.f / (float)D) + EPS);

    if (lane == 0) {
#pragma unroll
        for (int e = 0; e < 8; ++e) logits[t * 8 + e] = acc[e];
        int p0 = atomicAdd(&counts[e0], 1);
        lists[e0 * T + p0] = (t << 1) | 0; wlist[e0 * T + p0] = w0;
        int p1 = atomicAdd(&counts[e1], 1);
        lists[e1 * T + p1] = (t << 1) | 1; wlist[e1 * T + p1] = w1;
    }

#pragma unroll
    for (int i = 0; i < 12; ++i) {
        const int k = lane + 64 * i;
        xn[(size_t)t * D + k] = f2bf(xv[i] * rs);
        out[(size_t)t * D + k] = wsum * xv[i];
    }
}

// ---------------------------------------------------------------------------
// Prefix: offs[e] = exclusive prefix sum of counts.
// ---------------------------------------------------------------------------
__global__ void prefix_kernel(const int* __restrict__ counts, int* __restrict__ offs)
{
    if (threadIdx.x == 0 && blockIdx.x == 0) {
        int a = 0;
#pragma unroll
        for (int e = 0; e < 8; ++e) { offs[e] = a; a += counts[e]; }
    }
}

// ---------------------------------------------------------------------------
// GEMM1: H[offs[e]+row][f] = relu( xn[tok(row)] . wip[e][half*FH+f] )
// m97-style 128x128 tile, BK=64, 4 waves (2x2), 32x32x16 bf16 MFMA,
// A gathered per-lane via global_load_lds (per-lane global src is legal).
// grid: bid = ((mt*12 + nt) << 3) | e   (expert pinned to XCD slot)
// ---------------------------------------------------------------------------
__global__ __launch_bounds__(256)
void gemm1_kernel(const unsigned short* __restrict__ xn,
                  const unsigned short* __restrict__ wip,
                  const int* __restrict__ counts, const int* __restrict__ offs,
                  const int* __restrict__ lists,
                  unsigned short* __restrict__ H, int half)
{
    __shared__ unsigned short sA[128 * 64];
    __shared__ unsigned short sB[128 * 64];
    __shared__ int s_tok[128];

    const int bid = blockIdx.x;
    const int e  = bid & 7;
    const int mt = (bid >> 3) / 12;
    const int nt = (bid >> 3) % 12;
    const int cnt = counts[e];
    const int base = mt * 128;
    if (base >= cnt) return;
    const int offe = offs[e];

    const int tid = threadIdx.x;
    const int w = tid >> 6, l = tid & 63;
    const int lo = l & 31, hi = l >> 5;
    const int wr = w >> 1, wc = w & 1;

    if (tid < 128) {
        const int idx = base + tid;
        s_tok[tid] = (idx < cnt) ? (lists[e * T + idx] >> 1) : 0;
    }
    __syncthreads();

    const unsigned short* aSrc[4];
    const unsigned short* bSrc[4];
#pragma unroll
    for (int j = 0; j < 4; ++j) {
        const int r = (w * 4 + j) * 8 + (l >> 3);     // tile row staged by this lane
        aSrc[j] = xn + (size_t)s_tok[r] * D + (l & 7) * 8;
        bSrc[j] = wip + ((size_t)e * F + half * FH + nt * 128 + r) * D + (l & 7) * 8;
    }
    char* sAc = (char*)sA;
    char* sBc = (char*)sB;

    f32x16 acc00, acc01, acc10, acc11;
#pragma unroll
    for (int q = 0; q < 16; ++q) { acc00[q] = 0.f; acc01[q] = 0.f; acc10[q] = 0.f; acc11[q] = 0.f; }

    const int ao0 = (wr * 64 + lo) * 128 + hi * 16;
    const int ao1 = ao0 + 32 * 128;
    const int bo0 = (wc * 64 + lo) * 128 + hi * 16;
    const int bo1 = bo0 + 32 * 128;

    for (int kt = 0; kt < 12; ++kt) {
        const int k0 = kt * 64;
#pragma unroll
        for (int j = 0; j < 4; ++j) {
            GLL16(aSrc[j] + k0, sAc + (w * 4 + j) * 1024);
            GLL16(bSrc[j] + k0, sBc + (w * 4 + j) * 1024);
        }
        __syncthreads();
#pragma unroll
        for (int ks = 0; ks < 4; ++ks) {
            short8 a0 = *(const short8*)(sAc + ao0 + ks * 32);
            short8 a1 = *(const short8*)(sAc + ao1 + ks * 32);
            short8 b0 = *(const short8*)(sBc + bo0 + ks * 32);
            short8 b1 = *(const short8*)(sBc + bo1 + ks * 32);
            acc00 = mfma_bf16(a0, b0, acc00);
            acc01 = mfma_bf16(a0, b1, acc01);
            acc10 = mfma_bf16(a1, b0, acc10);
            acc11 = mfma_bf16(a1, b1, acc11);
        }
        __syncthreads();
    }

    // epilogue: relu -> bf16 -> H  (rows >= cnt clamped; packed layout)
    const int cbase = nt * 128 + wc * 64 + lo;
#pragma unroll
    for (int r = 0; r < 16; ++r) {
        const int crow = (r & 3) + 8 * (r >> 2) + 4 * hi;
        int lrow = wr * 64 + crow;
        if (base + lrow < cnt) {
            unsigned short* hp = H + (size_t)(offe + base + lrow) * FH + cbase;
            hp[0]  = f2bf(fmaxf(acc00[r], 0.f));
            hp[32] = f2bf(fmaxf(acc01[r], 0.f));
        }
        lrow += 32;
        if (base + lrow < cnt) {
            unsigned short* hp = H + (size_t)(offe + base + lrow) * FH + cbase;
            hp[0]  = f2bf(fmaxf(acc10[r], 0.f));
            hp[32] = f2bf(fmaxf(acc11[r], 0.f));
        }
    }
}

// ---------------------------------------------------------------------------
// GEMM2: out[tok][d] += w_tok * ( H[offs[e]+row] . wop[e][d][half*FH..] )
// Same 128x128 structure; K = 1536 per half. Epilogue: atomicAdd (each out
// element receives exactly 2 adds across the whole grid: one per slot).
// ---------------------------------------------------------------------------
__global__ __launch_bounds__(256)
void gemm2_kernel(const unsigned short* __restrict__ H,
                  const unsigned short* __restrict__ wop,
                  const int* __restrict__ counts, const int* __restrict__ offs,
                  const int* __restrict__ lists, const float* __restrict__ wlist,
                  float* __restrict__ out, int half)
{
    __shared__ unsigned short sA[128 * 64];
    __shared__ unsigned short sB[128 * 64];
    __shared__ int   s_tok[128];
    __shared__ float s_wgt[128];

    const int bid = blockIdx.x;
    const int e  = bid & 7;
    const int mt = (bid >> 3) / 6;
    const int nt = (bid >> 3) % 6;
    const int cnt = counts[e];
    const int base = mt * 128;
    if (base >= cnt) return;
    const int offe = offs[e];

    const int tid = threadIdx.x;
    const int w = tid >> 6, l = tid & 63;
    const int lo = l & 31, hi = l >> 5;
    const int wr = w >> 1, wc = w & 1;

    if (tid < 128) {
        const int idx = base + tid;
        const bool v = idx < cnt;
        s_tok[tid] = v ? lists[e * T + idx] : 0;
        s_wgt[tid] = v ? wlist[e * T + idx] : 0.f;
    }

    const unsigned short* aSrc[4];
    const unsigned short* bSrc[4];
#pragma unroll
    for (int j = 0; j < 4; ++j) {
        const int r = (w * 4 + j) * 8 + (l >> 3);
        aSrc[j] = H + (size_t)(offe + base + r) * FH + (l & 7) * 8;
        bSrc[j] = wop + ((size_t)e * D + nt * 128 + r) * F + half * FH + (l & 7) * 8;
    }
    char* sAc = (char*)sA;
    char* sBc = (char*)sB;

    f32x16 acc00, acc01, acc10, acc11;
#pragma unroll
    for (int q = 0; q < 16; ++q) { acc00[q] = 0.f; acc01[q] = 0.f; acc10[q] = 0.f; acc11[q] = 0.f; }

    const int ao0 = (wr * 64 + lo) * 128 + hi * 16;
    const int ao1 = ao0 + 32 * 128;
    const int bo0 = (wc * 64 + lo) * 128 + hi * 16;
    const int bo1 = bo0 + 32 * 128;

    for (int kt = 0; kt < 24; ++kt) {
        const int k0 = kt * 64;
#pragma unroll
        for (int j = 0; j < 4; ++j) {
            GLL16(aSrc[j] + k0, sAc + (w * 4 + j) * 1024);
            GLL16(bSrc[j] + k0, sBc + (w * 4 + j) * 1024);
        }
        __syncthreads();
#pragma unroll
        for (int ks = 0; ks < 4; ++ks) {
            short8 a0 = *(const short8*)(sAc + ao0 + ks * 32);
            short8 a1 = *(const short8*)(sAc + ao1 + ks * 32);
            short8 b0 = *(const short8*)(sBc + bo0 + ks * 32);
            short8 b1 = *(const short8*)(sBc + bo1 + ks * 32);
            acc00 = mfma_bf16(a0, b0, acc00);
            acc01 = mfma_bf16(a0, b1, acc01);
            acc10 = mfma_bf16(a1, b0, acc10);
            acc11 = mfma_bf16(a1, b1, acc11);
        }
        __syncthreads();
    }

    const int cbase = nt * 128 + wc * 64 + lo;
#pragma unroll
    for (int r = 0; r < 16; ++r) {
        const int crow = (r & 3) + 8 * (r >> 2) + 4 * hi;
        int lrow = wr * 64 + crow;
        if (base + lrow < cnt) {
            const int tk = s_tok[lrow] >> 1;
            const float wgt = s_wgt[lrow];
            float* dst = out + (size_t)tk * D + cbase;
            atomicAdd(dst,      wgt * acc00[r]);
            atomicAdd(dst + 32, wgt * acc01[r]);
        }
        lrow += 32;
        if (base + lrow < cnt) {
            const int tk = s_tok[lrow] >> 1;
            const float wgt = s_wgt[lrow];
            float* dst = out + (size_t)tk * D + cbase;
            atomicAdd(dst,      wgt * acc10[r]);
            atomicAdd(dst + 32, wgt * acc11[r]);
        }
    }
}

// ---------------------------------------------------------------------------
extern "C" void kernel_launch(void* const* d_in, const int* in_sizes, int n_in,
                              void* d_out, int out_size, void* d_ws, size_t ws_size,
                              hipStream_t stream) {
    const float* x   = (const float*)d_in[0];   // [T, D]
    const float* rw  = (const float*)d_in[1];   // [E, D]
    const float* lnw = (const float*)d_in[2];   // [E, D]
    const float* wi  = (const float*)d_in[3];   // [E, F, D]
    const float* wo  = (const float*)d_in[4];   // [E, D, F]

    float* out    = (float*)d_out;                    // [T, D]
    float* logits = (float*)d_out + (size_t)T * D;    // [T, E]

    char* ws = (char*)d_ws;
    int*            counts = (int*)(ws);                       // 32 B
    int*            offs   = (int*)(ws + 256);                 // 32 B
    int*            lists  = (int*)(ws + 1024);                // 256 KB
    float*          wlist  = (float*)(ws + 1024 + 262144);     // 256 KB
    unsigned short* xn     = (unsigned short*)(ws + 1048576);  // 12.6 MB
    unsigned short* wip    = (unsigned short*)(ws + 13631488); // 37.7 MB
    unsigned short* wop    = (unsigned short*)(ws + 51380224); // 37.7 MB
    unsigned short* H      = (unsigned short*)(ws + 89128960); // (16384+256)*1536*2 = 51.1 MB
    // total ws usage: ~140.2 MB

    hipMemsetAsync(counts, 0, 64, stream);

    convert_weights<<<36864, 256, 0, stream>>>(wi, wo, lnw, wip, wop);

    router_norm_kernel<<<T / 4, 256, 0, stream>>>(x, rw, logits, xn, out,
                                                  counts, lists, wlist);

    prefix_kernel<<<1, 1, 0, stream>>>(counts, offs);

    for (int h = 0; h < 2; ++h) {
        // worst-case grid (cap 4096 rows/expert); blocks early-exit past cnt
        gemm1_kernel<<<32 * 12 * 8, 256, 0, stream>>>(xn, wip, counts, offs,
                                                      lists, H, h);
        gemm2_kernel<<<32 * 6 * 8, 256, 0, stream>>>(H, wop, counts, offs,
                                                     lists, wlist, out, h);
    }
}

// Round 4
// 504.635 us; speedup vs baseline: 50.7793x; 1.3174x over previous
//
#include <hip/hip_runtime.h>
#include <hip/hip_bf16.h>
#include <math.h>

typedef short short8 __attribute__((ext_vector_type(8)));
typedef float f32x16 __attribute__((ext_vector_type(16)));

constexpr int D = 768;    // model dim
constexpr int E = 8;      // experts
constexpr int F = 3072;   // ffn dim
constexpr int FH = 1536;  // F half
constexpr int T = 8192;   // tokens
constexpr float EPS = 1e-6f;

static __device__ inline unsigned short f2bf(float f) {
    __hip_bfloat16 h = __float2bfloat16(f);
    return *reinterpret_cast<unsigned short*>(&h);
}

static __device__ inline f32x16 mfma_bf16(short8 a, short8 b, f32x16 c) {
    return __builtin_amdgcn_mfma_f32_32x32x16_bf16(a, b, c, 0, 0, 0);
}

// async global->LDS, 16B per lane; LDS dest = wave-uniform base + lane*16
#define GLL16(g, s) __builtin_amdgcn_global_load_lds( \
    (const __attribute__((address_space(1))) unsigned int*)(g), \
    (__attribute__((address_space(3))) unsigned int*)(s), 16, 0, 0)

// ---------------------------------------------------------------------------
// Weight conversion: wi' = bf16(wi * ln_w) (ln_w folded), wo' = bf16(wo).
// ---------------------------------------------------------------------------
__global__ __launch_bounds__(256)
void convert_weights(const float* __restrict__ wi, const float* __restrict__ wo,
                     const float* __restrict__ lnw,
                     unsigned short* __restrict__ wip, unsigned short* __restrict__ wop)
{
    const unsigned NWI = (unsigned)E * F * D;
    unsigned i4 = (blockIdx.x * 256u + threadIdx.x) * 4u;
    if (i4 < NWI) {
        float4 v = *(const float4*)(wi + i4);
        unsigned e = i4 / (unsigned)(F * D);
        unsigned d = i4 % (unsigned)D;
        float4 l = *(const float4*)(lnw + e * D + d);
        ushort4 o = { f2bf(v.x * l.x), f2bf(v.y * l.y), f2bf(v.z * l.z), f2bf(v.w * l.w) };
        *(ushort4*)(wip + i4) = o;
    } else {
        unsigned j = i4 - NWI;
        float4 v = *(const float4*)(wo + j);
        ushort4 o = { f2bf(v.x), f2bf(v.y), f2bf(v.z), f2bf(v.w) };
        *(ushort4*)(wop + j) = o;
    }
}

// ---------------------------------------------------------------------------
// Router + RMS-norm: logits (exact fp32), top-2, xn = bf16(x*rstd),
// out = wsum*x (residual term), per-token meta (sel, w01). NO atomics.
// One 64-lane wave per token.
// ---------------------------------------------------------------------------
__global__ __launch_bounds__(256)
void router_norm_kernel(const float* __restrict__ x,
                        const float* __restrict__ rw,
                        float* __restrict__ logits,        // [T, E]
                        unsigned short* __restrict__ xn,   // [T, D] bf16
                        float* __restrict__ out,           // [T, D] <- wsum*x
                        int*   __restrict__ sel,           // [T] e0 | e1<<4
                        float2* __restrict__ w01)          // [T] (w0, w1)
{
    const int lane = threadIdx.x & 63;
    const int wid  = threadIdx.x >> 6;
    const int t = blockIdx.x * 4 + wid;
    if (t >= T) return;

    const float* xr = x + (size_t)t * D;
    float xv[12];
    float acc[8];
#pragma unroll
    for (int e = 0; e < 8; ++e) acc[e] = 0.f;
    float ssq = 0.f;
#pragma unroll
    for (int i = 0; i < 12; ++i) {
        const int k = lane + 64 * i;
        const float v = xr[k];
        xv[i] = v;
        ssq += v * v;
#pragma unroll
        for (int e = 0; e < 8; ++e) acc[e] += v * rw[e * D + k];
    }
#pragma unroll
    for (int off = 32; off; off >>= 1) {
        ssq += __shfl_xor(ssq, off);
#pragma unroll
        for (int e = 0; e < 8; ++e) acc[e] += __shfl_xor(acc[e], off);
    }

    int e0 = 0; float m0 = acc[0];
#pragma unroll
    for (int e = 1; e < 8; ++e) if (acc[e] > m0) { m0 = acc[e]; e0 = e; }
    int e1 = -1; float m1 = -3.4e38f;
#pragma unroll
    for (int e = 0; e < 8; ++e) if (e != e0 && acc[e] > m1) { m1 = acc[e]; e1 = e; }

    const float r  = expf(m1 - m0);
    const float w0 = 1.f / (1.f + r);
    const float w1 = r * w0;
    const float wsum = w0 + w1;
    const float rs = rsqrtf(ssq * (1.f / (float)D) + EPS);

    if (lane == 0) {
#pragma unroll
        for (int e = 0; e < 8; ++e) logits[t * 8 + e] = acc[e];
        sel[t] = e0 | (e1 << 4);
        w01[t] = make_float2(w0, w1);
    }

#pragma unroll
    for (int i = 0; i < 12; ++i) {
        const int k = lane + 64 * i;
        xn[(size_t)t * D + k] = f2bf(xv[i] * rs);
        out[(size_t)t * D + k] = wsum * xv[i];
    }
}

// ---------------------------------------------------------------------------
// List build: one block per expert, ballot/prefix compaction. Zero atomics;
// lists are token-ordered and deterministic. Writes counts[e] once.
// ---------------------------------------------------------------------------
__global__ __launch_bounds__(256)
void build_lists(const int* __restrict__ sel, const float2* __restrict__ w01,
                 int* __restrict__ counts, int* __restrict__ lists,
                 float* __restrict__ wlist)
{
    const int e = blockIdx.x;
    const int tid = threadIdx.x;
    const int lane = tid & 63;
    const int wv = tid >> 6;
    __shared__ int wtot[4];
    int cnt = 0;
    for (int c0 = 0; c0 < T; c0 += 256) {
        const int t = c0 + tid;
        const int s = sel[t];
        const bool m1 = ((s >> 4) & 15) == e;
        const bool m = ((s & 15) == e) || m1;
        const unsigned long long b = __ballot(m);
        const int pre = __popcll(b & ((1ULL << lane) - 1ULL));
        if (lane == 0) wtot[wv] = __popcll(b);
        __syncthreads();
        int wbase = 0;
#pragma unroll
        for (int i = 0; i < 4; ++i) if (i < wv) wbase += wtot[i];
        if (m) {
            const int pos = cnt + wbase + pre;
            lists[e * T + pos] = (t << 1) | (m1 ? 1 : 0);
            const float2 w = w01[t];
            wlist[e * T + pos] = m1 ? w.y : w.x;
        }
        cnt += wtot[0] + wtot[1] + wtot[2] + wtot[3];
        __syncthreads();
    }
    if (tid == 0) counts[e] = cnt;
}

// ---------------------------------------------------------------------------
// GEMM1: H[offs[e]+row][f] = relu( xn[tok(row)] . wip[e][half*FH+f] )
// m97-style 128x128 tile, BK=64, 4 waves (2x2), 32x32x16 bf16 MFMA,
// A gathered per-lane via global_load_lds (per-lane global src is legal).
// grid: bid = ((mt*12 + nt) << 3) | e   (expert pinned to XCD slot)
// ---------------------------------------------------------------------------
__global__ __launch_bounds__(256)
void gemm1_kernel(const unsigned short* __restrict__ xn,
                  const unsigned short* __restrict__ wip,
                  const int* __restrict__ counts,
                  const int* __restrict__ lists,
                  unsigned short* __restrict__ H, int half)
{
    __shared__ unsigned short sA[128 * 64];
    __shared__ unsigned short sB[128 * 64];
    __shared__ int s_tok[128];

    const int bid = blockIdx.x;
    const int e  = bid & 7;
    const int mt = (bid >> 3) / 12;
    const int nt = (bid >> 3) % 12;
    const int cnt = counts[e];
    const int base = mt * 128;
    if (base >= cnt) return;
    int offe = 0;
    for (int i = 0; i < e; ++i) offe += counts[i];

    const int tid = threadIdx.x;
    const int w = tid >> 6, l = tid & 63;
    const int lo = l & 31, hi = l >> 5;
    const int wr = w >> 1, wc = w & 1;

    if (tid < 128) {
        const int idx = base + tid;
        s_tok[tid] = (idx < cnt) ? (lists[e * T + idx] >> 1) : 0;
    }
    __syncthreads();

    const unsigned short* aSrc[4];
    const unsigned short* bSrc[4];
#pragma unroll
    for (int j = 0; j < 4; ++j) {
        const int r = (w * 4 + j) * 8 + (l >> 3);     // tile row staged by this lane
        aSrc[j] = xn + (size_t)s_tok[r] * D + (l & 7) * 8;
        bSrc[j] = wip + ((size_t)e * F + half * FH + nt * 128 + r) * D + (l & 7) * 8;
    }
    char* sAc = (char*)sA;
    char* sBc = (char*)sB;

    f32x16 acc00, acc01, acc10, acc11;
#pragma unroll
    for (int q = 0; q < 16; ++q) { acc00[q] = 0.f; acc01[q] = 0.f; acc10[q] = 0.f; acc11[q] = 0.f; }

    const int ao0 = (wr * 64 + lo) * 128 + hi * 16;
    const int ao1 = ao0 + 32 * 128;
    const int bo0 = (wc * 64 + lo) * 128 + hi * 16;
    const int bo1 = bo0 + 32 * 128;

    for (int kt = 0; kt < 12; ++kt) {
        const int k0 = kt * 64;
#pragma unroll
        for (int j = 0; j < 4; ++j) {
            GLL16(aSrc[j] + k0, sAc + (w * 4 + j) * 1024);
            GLL16(bSrc[j] + k0, sBc + (w * 4 + j) * 1024);
        }
        __syncthreads();
#pragma unroll
        for (int ks = 0; ks < 4; ++ks) {
            short8 a0 = *(const short8*)(sAc + ao0 + ks * 32);
            short8 a1 = *(const short8*)(sAc + ao1 + ks * 32);
            short8 b0 = *(const short8*)(sBc + bo0 + ks * 32);
            short8 b1 = *(const short8*)(sBc + bo1 + ks * 32);
            acc00 = mfma_bf16(a0, b0, acc00);
            acc01 = mfma_bf16(a0, b1, acc01);
            acc10 = mfma_bf16(a1, b0, acc10);
            acc11 = mfma_bf16(a1, b1, acc11);
        }
        __syncthreads();
    }

    // epilogue: relu -> bf16 -> H  (rows >= cnt clamped; packed layout)
    const int cbase = nt * 128 + wc * 64 + lo;
#pragma unroll
    for (int r = 0; r < 16; ++r) {
        const int crow = (r & 3) + 8 * (r >> 2) + 4 * hi;
        int lrow = wr * 64 + crow;
        if (base + lrow < cnt) {
            unsigned short* hp = H + (size_t)(offe + base + lrow) * FH + cbase;
            hp[0]  = f2bf(fmaxf(acc00[r], 0.f));
            hp[32] = f2bf(fmaxf(acc01[r], 0.f));
        }
        lrow += 32;
        if (base + lrow < cnt) {
            unsigned short* hp = H + (size_t)(offe + base + lrow) * FH + cbase;
            hp[0]  = f2bf(fmaxf(acc10[r], 0.f));
            hp[32] = f2bf(fmaxf(acc11[r], 0.f));
        }
    }
}

// ---------------------------------------------------------------------------
// GEMM2: out[tok][d] += w_tok * ( H[offs[e]+row] . wop[e][d][half*FH..] )
// Same 128x128 structure; K = 1536 per half. Epilogue: atomicAdd (each out
// element receives exactly 2 adds across the whole grid: one per slot).
// ---------------------------------------------------------------------------
__global__ __launch_bounds__(256)
void gemm2_kernel(const unsigned short* __restrict__ H,
                  const unsigned short* __restrict__ wop,
                  const int* __restrict__ counts,
                  const int* __restrict__ lists, const float* __restrict__ wlist,
                  float* __restrict__ out, int half)
{
    __shared__ unsigned short sA[128 * 64];
    __shared__ unsigned short sB[128 * 64];
    __shared__ int   s_tok[128];
    __shared__ float s_wgt[128];

    const int bid = blockIdx.x;
    const int e  = bid & 7;
    const int mt = (bid >> 3) / 6;
    const int nt = (bid >> 3) % 6;
    const int cnt = counts[e];
    const int base = mt * 128;
    if (base >= cnt) return;
    int offe = 0;
    for (int i = 0; i < e; ++i) offe += counts[i];

    const int tid = threadIdx.x;
    const int w = tid >> 6, l = tid & 63;
    const int lo = l & 31, hi = l >> 5;
    const int wr = w >> 1, wc = w & 1;

    if (tid < 128) {
        const int idx = base + tid;
        const bool v = idx < cnt;
        s_tok[tid] = v ? lists[e * T + idx] : 0;
        s_wgt[tid] = v ? wlist[e * T + idx] : 0.f;
    }

    const unsigned short* aSrc[4];
    const unsigned short* bSrc[4];
#pragma unroll
    for (int j = 0; j < 4; ++j) {
        const int r = (w * 4 + j) * 8 + (l >> 3);
        aSrc[j] = H + (size_t)(offe + base + r) * FH + (l & 7) * 8;
        bSrc[j] = wop + ((size_t)e * D + nt * 128 + r) * F + half * FH + (l & 7) * 8;
    }
    char* sAc = (char*)sA;
    char* sBc = (char*)sB;

    f32x16 acc00, acc01, acc10, acc11;
#pragma unroll
    for (int q = 0; q < 16; ++q) { acc00[q] = 0.f; acc01[q] = 0.f; acc10[q] = 0.f; acc11[q] = 0.f; }

    const int ao0 = (wr * 64 + lo) * 128 + hi * 16;
    const int ao1 = ao0 + 32 * 128;
    const int bo0 = (wc * 64 + lo) * 128 + hi * 16;
    const int bo1 = bo0 + 32 * 128;

    for (int kt = 0; kt < 24; ++kt) {
        const int k0 = kt * 64;
#pragma unroll
        for (int j = 0; j < 4; ++j) {
            GLL16(aSrc[j] + k0, sAc + (w * 4 + j) * 1024);
            GLL16(bSrc[j] + k0, sBc + (w * 4 + j) * 1024);
        }
        __syncthreads();
#pragma unroll
        for (int ks = 0; ks < 4; ++ks) {
            short8 a0 = *(const short8*)(sAc + ao0 + ks * 32);
            short8 a1 = *(const short8*)(sAc + ao1 + ks * 32);
            short8 b0 = *(const short8*)(sBc + bo0 + ks * 32);
            short8 b1 = *(const short8*)(sBc + bo1 + ks * 32);
            acc00 = mfma_bf16(a0, b0, acc00);
            acc01 = mfma_bf16(a0, b1, acc01);
            acc10 = mfma_bf16(a1, b0, acc10);
            acc11 = mfma_bf16(a1, b1, acc11);
        }
        __syncthreads();
    }

    const int cbase = nt * 128 + wc * 64 + lo;
#pragma unroll
    for (int r = 0; r < 16; ++r) {
        const int crow = (r & 3) + 8 * (r >> 2) + 4 * hi;
        int lrow = wr * 64 + crow;
        if (base + lrow < cnt) {
            const int tk = s_tok[lrow] >> 1;
            const float wgt = s_wgt[lrow];
            float* dst = out + (size_t)tk * D + cbase;
            atomicAdd(dst,      wgt * acc00[r]);
            atomicAdd(dst + 32, wgt * acc01[r]);
        }
        lrow += 32;
        if (base + lrow < cnt) {
            const int tk = s_tok[lrow] >> 1;
            const float wgt = s_wgt[lrow];
            float* dst = out + (size_t)tk * D + cbase;
            atomicAdd(dst,      wgt * acc10[r]);
            atomicAdd(dst + 32, wgt * acc11[r]);
        }
    }
}

// ---------------------------------------------------------------------------
extern "C" void kernel_launch(void* const* d_in, const int* in_sizes, int n_in,
                              void* d_out, int out_size, void* d_ws, size_t ws_size,
                              hipStream_t stream) {
    const float* x   = (const float*)d_in[0];   // [T, D]
    const float* rw  = (const float*)d_in[1];   // [E, D]
    const float* lnw = (const float*)d_in[2];   // [E, D]
    const float* wi  = (const float*)d_in[3];   // [E, F, D]
    const float* wo  = (const float*)d_in[4];   // [E, D, F]

    float* out    = (float*)d_out;                    // [T, D]
    float* logits = (float*)d_out + (size_t)T * D;    // [T, E]

    char* ws = (char*)d_ws;
    int*            counts = (int*)(ws);                       // 64 B
    int*            sel    = (int*)(ws + 4096);                // 32 KB
    float2*         w01    = (float2*)(ws + 65536);            // 64 KB
    int*            lists  = (int*)(ws + 131072);              // 256 KB
    float*          wlist  = (float*)(ws + 393216);            // 256 KB
    unsigned short* xn     = (unsigned short*)(ws + 1048576);  // 12.6 MB
    unsigned short* wip    = (unsigned short*)(ws + 13631488); // 37.7 MB
    unsigned short* wop    = (unsigned short*)(ws + 51380224); // 37.7 MB
    unsigned short* H      = (unsigned short*)(ws + 89128960); // 51.1 MB
    // total ws usage: ~140.2 MB

    convert_weights<<<36864, 256, 0, stream>>>(wi, wo, lnw, wip, wop);

    router_norm_kernel<<<T / 4, 256, 0, stream>>>(x, rw, logits, xn, out,
                                                  sel, w01);

    build_lists<<<E, 256, 0, stream>>>(sel, w01, counts, lists, wlist);

    for (int h = 0; h < 2; ++h) {
        // worst-case grid (cap 4096 rows/expert); blocks early-exit past cnt
        gemm1_kernel<<<32 * 12 * 8, 256, 0, stream>>>(xn, wip, counts,
                                                      lists, H, h);
        gemm2_kernel<<<32 * 6 * 8, 256, 0, stream>>>(H, wop, counts,
                                                     lists, wlist, out, h);
    }
}

// Round 5
// 375.830 us; speedup vs baseline: 68.1825x; 1.3427x over previous
//
#include <hip/hip_runtime.h>
#include <hip/hip_bf16.h>
#include <math.h>

typedef short short8 __attribute__((ext_vector_type(8)));
typedef float f32x16 __attribute__((ext_vector_type(16)));

constexpr int D = 768;    // model dim
constexpr int E = 8;      // experts
constexpr int F = 3072;   // ffn dim
constexpr int FH = 1536;  // F half
constexpr int T = 8192;   // tokens
constexpr float EPS = 1e-6f;

static __device__ inline unsigned short f2bf(float f) {
    __hip_bfloat16 h = __float2bfloat16(f);
    return *reinterpret_cast<unsigned short*>(&h);
}

static __device__ inline f32x16 mfma_bf16(short8 a, short8 b, f32x16 c) {
    return __builtin_amdgcn_mfma_f32_32x32x16_bf16(a, b, c, 0, 0, 0);
}

// async global->LDS, 16B per lane; LDS dest = wave-uniform base + lane*16
#define GLL16(g, s) __builtin_amdgcn_global_load_lds( \
    (const __attribute__((address_space(1))) unsigned int*)(g), \
    (__attribute__((address_space(3))) unsigned int*)(s), 16, 0, 0)

// ---------------------------------------------------------------------------
// Weight conversion: wi' = bf16(wi * ln_w) (ln_w folded), wo' = bf16(wo).
// ---------------------------------------------------------------------------
__global__ __launch_bounds__(256)
void convert_weights(const float* __restrict__ wi, const float* __restrict__ wo,
                     const float* __restrict__ lnw,
                     unsigned short* __restrict__ wip, unsigned short* __restrict__ wop)
{
    const unsigned NWI = (unsigned)E * F * D;
    unsigned i4 = (blockIdx.x * 256u + threadIdx.x) * 4u;
    if (i4 < NWI) {
        float4 v = *(const float4*)(wi + i4);
        unsigned e = i4 / (unsigned)(F * D);
        unsigned d = i4 % (unsigned)D;
        float4 l = *(const float4*)(lnw + e * D + d);
        ushort4 o = { f2bf(v.x * l.x), f2bf(v.y * l.y), f2bf(v.z * l.z), f2bf(v.w * l.w) };
        *(ushort4*)(wip + i4) = o;
    } else {
        unsigned j = i4 - NWI;
        float4 v = *(const float4*)(wo + j);
        ushort4 o = { f2bf(v.x), f2bf(v.y), f2bf(v.z), f2bf(v.w) };
        *(ushort4*)(wop + j) = o;
    }
}

// ---------------------------------------------------------------------------
// Router + RMS-norm: logits (exact fp32), top-2, xn = bf16(x*rstd),
// out = wsum*x (residual term), per-token meta (sel, w01). NO atomics.
// One 64-lane wave per token.
// ---------------------------------------------------------------------------
__global__ __launch_bounds__(256)
void router_norm_kernel(const float* __restrict__ x,
                        const float* __restrict__ rw,
                        float* __restrict__ logits,        // [T, E]
                        unsigned short* __restrict__ xn,   // [T, D] bf16
                        float* __restrict__ out,           // [T, D] <- wsum*x
                        int*   __restrict__ sel,           // [T] e0 | e1<<4
                        float2* __restrict__ w01)          // [T] (w0, w1)
{
    const int lane = threadIdx.x & 63;
    const int wid  = threadIdx.x >> 6;
    const int t = blockIdx.x * 4 + wid;
    if (t >= T) return;

    const float* xr = x + (size_t)t * D;
    float xv[12];
    float acc[8];
#pragma unroll
    for (int e = 0; e < 8; ++e) acc[e] = 0.f;
    float ssq = 0.f;
#pragma unroll
    for (int i = 0; i < 12; ++i) {
        const int k = lane + 64 * i;
        const float v = xr[k];
        xv[i] = v;
        ssq += v * v;
#pragma unroll
        for (int e = 0; e < 8; ++e) acc[e] += v * rw[e * D + k];
    }
#pragma unroll
    for (int off = 32; off; off >>= 1) {
        ssq += __shfl_xor(ssq, off);
#pragma unroll
        for (int e = 0; e < 8; ++e) acc[e] += __shfl_xor(acc[e], off);
    }

    int e0 = 0; float m0 = acc[0];
#pragma unroll
    for (int e = 1; e < 8; ++e) if (acc[e] > m0) { m0 = acc[e]; e0 = e; }
    int e1 = -1; float m1 = -3.4e38f;
#pragma unroll
    for (int e = 0; e < 8; ++e) if (e != e0 && acc[e] > m1) { m1 = acc[e]; e1 = e; }

    const float r  = expf(m1 - m0);
    const float w0 = 1.f / (1.f + r);
    const float w1 = r * w0;
    const float wsum = w0 + w1;
    const float rs = rsqrtf(ssq * (1.f / (float)D) + EPS);

    if (lane == 0) {
#pragma unroll
        for (int e = 0; e < 8; ++e) logits[t * 8 + e] = acc[e];
        sel[t] = e0 | (e1 << 4);
        w01[t] = make_float2(w0, w1);
    }

#pragma unroll
    for (int i = 0; i < 12; ++i) {
        const int k = lane + 64 * i;
        xn[(size_t)t * D + k] = f2bf(xv[i] * rs);
        out[(size_t)t * D + k] = wsum * xv[i];
    }
}

// ---------------------------------------------------------------------------
// List build: one block per expert, ballot/prefix compaction. Zero atomics;
// lists are token-ordered and deterministic. Writes counts[e] once.
// ---------------------------------------------------------------------------
__global__ __launch_bounds__(256)
void build_lists(const int* __restrict__ sel, const float2* __restrict__ w01,
                 int* __restrict__ counts, int* __restrict__ lists,
                 float* __restrict__ wlist)
{
    const int e = blockIdx.x;
    const int tid = threadIdx.x;
    const int lane = tid & 63;
    const int wv = tid >> 6;
    __shared__ int wtot[4];
    int cnt = 0;
    for (int c0 = 0; c0 < T; c0 += 256) {
        const int t = c0 + tid;
        const int s = sel[t];
        const bool m1 = ((s >> 4) & 15) == e;
        const bool m = ((s & 15) == e) || m1;
        const unsigned long long b = __ballot(m);
        const int pre = __popcll(b & ((1ULL << lane) - 1ULL));
        if (lane == 0) wtot[wv] = __popcll(b);
        __syncthreads();
        int wbase = 0;
#pragma unroll
        for (int i = 0; i < 4; ++i) if (i < wv) wbase += wtot[i];
        if (m) {
            const int pos = cnt + wbase + pre;
            lists[e * T + pos] = (t << 1) | (m1 ? 1 : 0);
            const float2 w = w01[t];
            wlist[e * T + pos] = m1 ? w.y : w.x;
        }
        cnt += wtot[0] + wtot[1] + wtot[2] + wtot[3];
        __syncthreads();
    }
    if (tid == 0) counts[e] = cnt;
}

// ---------------------------------------------------------------------------
// GEMM1: H[offs[e]+row][f] = relu( xn[tok(row)] . wip[e][half*FH+f] )
// 128x128 tile, BK=64, 4 waves, 32x32x16 bf16 MFMA.
// Minimum-2-phase double buffer: STAGE(next) issued before compute(cur);
// one barrier per K-step (auto vmcnt/lgkm drain). T2 XOR-swizzle:
// linear LDS dest + inverse-swizzled global source + swizzled ds_read.
// ---------------------------------------------------------------------------
__global__ __launch_bounds__(256)
void gemm1_kernel(const unsigned short* __restrict__ xn,
                  const unsigned short* __restrict__ wip,
                  const int* __restrict__ counts,
                  const int* __restrict__ lists,
                  unsigned short* __restrict__ H, int half)
{
    __shared__ __align__(16) char smem[65536];   // 2 x (sA 16K + sB 16K)
    __shared__ int s_tok[128];

    const int bid = blockIdx.x;
    const int e  = bid & 7;
    const int mt = (bid >> 3) / 12;
    const int nt = (bid >> 3) % 12;
    const int cnt = counts[e];
    const int base = mt * 128;
    if (base >= cnt) return;
    int offe = 0;
    for (int i = 0; i < e; ++i) offe += counts[i];

    const int tid = threadIdx.x;
    const int w = tid >> 6, l = tid & 63;
    const int lo = l & 31, hi = l >> 5;
    const int wr = w >> 1, wc = w & 1;

    if (tid < 128) {
        const int idx = base + tid;
        s_tok[tid] = (idx < cnt) ? (lists[e * T + idx] >> 1) : 0;
    }
    __syncthreads();

    // inverse-swizzled global source chunk (16B units within each 128B span)
    const int r = (w * 4 + 0) * 8 + (l >> 3);          // row staged by j=0
    const int chS = ((l & 7) ^ ((l >> 3) & 7)) * 8;    // swizzled chunk, in shorts
    const unsigned short* aSrc[4];
    const unsigned short* bSrc[4];
#pragma unroll
    for (int j = 0; j < 4; ++j) {
        const int rj = r + j * 8;
        aSrc[j] = xn + (size_t)s_tok[rj] * D + chS;
        bSrc[j] = wip + ((size_t)e * F + half * FH + nt * 128 + rj) * D + chS;
    }

    f32x16 acc00, acc01, acc10, acc11;
#pragma unroll
    for (int q = 0; q < 16; ++q) { acc00[q] = 0.f; acc01[q] = 0.f; acc10[q] = 0.f; acc11[q] = 0.f; }

    const int rx = (lo & 7) << 4;                   // read-side row XOR
    const int arow0 = (wr * 64 + lo) * 128;
    const int arow1 = arow0 + 32 * 128;
    const int brow0 = (wc * 64 + lo) * 128;
    const int brow1 = brow0 + 32 * 128;
    const int stgOff = w * 4096;                    // 4 x 1024B per wave

    // prologue: stage tile 0 into buf 0
#pragma unroll
    for (int j = 0; j < 4; ++j) {
        GLL16(aSrc[j], smem + stgOff + j * 1024);
        GLL16(bSrc[j], smem + 16384 + stgOff + j * 1024);
    }
    __syncthreads();

    int cur = 0;
    for (int kt = 0; kt < 12; ++kt) {
        const char* bufA = smem + (cur ^ 1) * 32768;   // stage target
        if (kt < 11) {
            const int k1 = (kt + 1) * 64;
#pragma unroll
            for (int j = 0; j < 4; ++j) {
                GLL16(aSrc[j] + k1, bufA + stgOff + j * 1024);
                GLL16(bSrc[j] + k1, bufA + 16384 + stgOff + j * 1024);
            }
        }
        const char* cA = smem + cur * 32768;
        const char* cB = cA + 16384;
#pragma unroll
        for (int ks = 0; ks < 4; ++ks) {
            const int coff = (hi * 16 + ks * 32) ^ rx;
            short8 a0 = *(const short8*)(cA + arow0 + coff);
            short8 a1 = *(const short8*)(cA + arow1 + coff);
            short8 b0 = *(const short8*)(cB + brow0 + coff);
            short8 b1 = *(const short8*)(cB + brow1 + coff);
            acc00 = mfma_bf16(a0, b0, acc00);
            acc01 = mfma_bf16(a0, b1, acc01);
            acc10 = mfma_bf16(a1, b0, acc10);
            acc11 = mfma_bf16(a1, b1, acc11);
        }
        __syncthreads();   // drains vmcnt (stage) + protects buf swap
        cur ^= 1;
    }

    // epilogue: relu -> bf16 -> H  (rows >= cnt clamped; packed layout)
    const int cbase = nt * 128 + wc * 64 + lo;
#pragma unroll
    for (int rr = 0; rr < 16; ++rr) {
        const int crow = (rr & 3) + 8 * (rr >> 2) + 4 * hi;
        int lrow = wr * 64 + crow;
        if (base + lrow < cnt) {
            unsigned short* hp = H + (size_t)(offe + base + lrow) * FH + cbase;
            hp[0]  = f2bf(fmaxf(acc00[rr], 0.f));
            hp[32] = f2bf(fmaxf(acc01[rr], 0.f));
        }
        lrow += 32;
        if (base + lrow < cnt) {
            unsigned short* hp = H + (size_t)(offe + base + lrow) * FH + cbase;
            hp[0]  = f2bf(fmaxf(acc10[rr], 0.f));
            hp[32] = f2bf(fmaxf(acc11[rr], 0.f));
        }
    }
}

// ---------------------------------------------------------------------------
// GEMM2: out[tok][d] += w_tok * ( H[offs[e]+row] . wop[e][d][half*FH..] )
// Same dbuf + swizzle structure; K = 1536 per half (24 steps).
// Epilogue: atomicAdd (each out element gets exactly 2 adds per half).
// ---------------------------------------------------------------------------
__global__ __launch_bounds__(256)
void gemm2_kernel(const unsigned short* __restrict__ H,
                  const unsigned short* __restrict__ wop,
                  const int* __restrict__ counts,
                  const int* __restrict__ lists, const float* __restrict__ wlist,
                  float* __restrict__ out, int half)
{
    __shared__ __align__(16) char smem[65536];
    __shared__ int   s_tok[128];
    __shared__ float s_wgt[128];

    const int bid = blockIdx.x;
    const int e  = bid & 7;
    const int mt = (bid >> 3) / 6;
    const int nt = (bid >> 3) % 6;
    const int cnt = counts[e];
    const int base = mt * 128;
    if (base >= cnt) return;
    int offe = 0;
    for (int i = 0; i < e; ++i) offe += counts[i];

    const int tid = threadIdx.x;
    const int w = tid >> 6, l = tid & 63;
    const int lo = l & 31, hi = l >> 5;
    const int wr = w >> 1, wc = w & 1;

    if (tid < 128) {
        const int idx = base + tid;
        const bool v = idx < cnt;
        s_tok[tid] = v ? lists[e * T + idx] : 0;
        s_wgt[tid] = v ? wlist[e * T + idx] : 0.f;
    }

    const int r = (w * 4 + 0) * 8 + (l >> 3);
    const int chS = ((l & 7) ^ ((l >> 3) & 7)) * 8;
    const unsigned short* aSrc[4];
    const unsigned short* bSrc[4];
#pragma unroll
    for (int j = 0; j < 4; ++j) {
        const int rj = r + j * 8;
        aSrc[j] = H + (size_t)(offe + base + rj) * FH + chS;
        bSrc[j] = wop + ((size_t)e * D + nt * 128 + rj) * F + half * FH + chS;
    }

    f32x16 acc00, acc01, acc10, acc11;
#pragma unroll
    for (int q = 0; q < 16; ++q) { acc00[q] = 0.f; acc01[q] = 0.f; acc10[q] = 0.f; acc11[q] = 0.f; }

    const int rx = (lo & 7) << 4;
    const int arow0 = (wr * 64 + lo) * 128;
    const int arow1 = arow0 + 32 * 128;
    const int brow0 = (wc * 64 + lo) * 128;
    const int brow1 = brow0 + 32 * 128;
    const int stgOff = w * 4096;

#pragma unroll
    for (int j = 0; j < 4; ++j) {
        GLL16(aSrc[j], smem + stgOff + j * 1024);
        GLL16(bSrc[j], smem + 16384 + stgOff + j * 1024);
    }
    __syncthreads();

    int cur = 0;
    for (int kt = 0; kt < 24; ++kt) {
        const char* bufA = smem + (cur ^ 1) * 32768;
        if (kt < 23) {
            const int k1 = (kt + 1) * 64;
#pragma unroll
            for (int j = 0; j < 4; ++j) {
                GLL16(aSrc[j] + k1, bufA + stgOff + j * 1024);
                GLL16(bSrc[j] + k1, bufA + 16384 + stgOff + j * 1024);
            }
        }
        const char* cA = smem + cur * 32768;
        const char* cB = cA + 16384;
#pragma unroll
        for (int ks = 0; ks < 4; ++ks) {
            const int coff = (hi * 16 + ks * 32) ^ rx;
            short8 a0 = *(const short8*)(cA + arow0 + coff);
            short8 a1 = *(const short8*)(cA + arow1 + coff);
            short8 b0 = *(const short8*)(cB + brow0 + coff);
            short8 b1 = *(const short8*)(cB + brow1 + coff);
            acc00 = mfma_bf16(a0, b0, acc00);
            acc01 = mfma_bf16(a0, b1, acc01);
            acc10 = mfma_bf16(a1, b0, acc10);
            acc11 = mfma_bf16(a1, b1, acc11);
        }
        __syncthreads();
        cur ^= 1;
    }

    const int cbase = nt * 128 + wc * 64 + lo;
#pragma unroll
    for (int rr = 0; rr < 16; ++rr) {
        const int crow = (rr & 3) + 8 * (rr >> 2) + 4 * hi;
        int lrow = wr * 64 + crow;
        if (base + lrow < cnt) {
            const int tk = s_tok[lrow] >> 1;
            const float wgt = s_wgt[lrow];
            float* dst = out + (size_t)tk * D + cbase;
            atomicAdd(dst,      wgt * acc00[rr]);
            atomicAdd(dst + 32, wgt * acc01[rr]);
        }
        lrow += 32;
        if (base + lrow < cnt) {
            const int tk = s_tok[lrow] >> 1;
            const float wgt = s_wgt[lrow];
            float* dst = out + (size_t)tk * D + cbase;
            atomicAdd(dst,      wgt * acc10[rr]);
            atomicAdd(dst + 32, wgt * acc11[rr]);
        }
    }
}

// ---------------------------------------------------------------------------
extern "C" void kernel_launch(void* const* d_in, const int* in_sizes, int n_in,
                              void* d_out, int out_size, void* d_ws, size_t ws_size,
                              hipStream_t stream) {
    const float* x   = (const float*)d_in[0];   // [T, D]
    const float* rw  = (const float*)d_in[1];   // [E, D]
    const float* lnw = (const float*)d_in[2];   // [E, D]
    const float* wi  = (const float*)d_in[3];   // [E, F, D]
    const float* wo  = (const float*)d_in[4];   // [E, D, F]

    float* out    = (float*)d_out;                    // [T, D]
    float* logits = (float*)d_out + (size_t)T * D;    // [T, E]

    char* ws = (char*)d_ws;
    int*            counts = (int*)(ws);                       // 64 B
    int*            sel    = (int*)(ws + 4096);                // 32 KB
    float2*         w01    = (float2*)(ws + 65536);            // 64 KB
    int*            lists  = (int*)(ws + 131072);              // 256 KB
    float*          wlist  = (float*)(ws + 393216);            // 256 KB
    unsigned short* xn     = (unsigned short*)(ws + 1048576);  // 12.6 MB
    unsigned short* wip    = (unsigned short*)(ws + 13631488); // 37.7 MB
    unsigned short* wop    = (unsigned short*)(ws + 51380224); // 37.7 MB
    unsigned short* H      = (unsigned short*)(ws + 89128960); // 51.1 MB
    // total ws usage: ~140.2 MB

    convert_weights<<<36864, 256, 0, stream>>>(wi, wo, lnw, wip, wop);

    router_norm_kernel<<<T / 4, 256, 0, stream>>>(x, rw, logits, xn, out,
                                                  sel, w01);

    build_lists<<<E, 256, 0, stream>>>(sel, w01, counts, lists, wlist);

    for (int h = 0; h < 2; ++h) {
        // worst-case grid (cap 4096 rows/expert); blocks early-exit past cnt
        gemm1_kernel<<<32 * 12 * 8, 256, 0, stream>>>(xn, wip, counts,
                                                      lists, H, h);
        gemm2_kernel<<<32 * 6 * 8, 256, 0, stream>>>(H, wop, counts,
                                                     lists, wlist, out, h);
    }
}

// Round 6
// 363.922 us; speedup vs baseline: 70.4134x; 1.0327x over previous
//
#include <hip/hip_runtime.h>
#include <hip/hip_bf16.h>
#include <math.h>

typedef short short8 __attribute__((ext_vector_type(8)));
typedef float f32x16 __attribute__((ext_vector_type(16)));

constexpr int D = 768;    // model dim
constexpr int E = 8;      // experts
constexpr int F = 3072;   // ffn dim
constexpr int FH = 1536;  // F half
constexpr int T = 8192;   // tokens
constexpr float EPS = 1e-6f;

static __device__ inline unsigned short f2bf(float f) {
    __hip_bfloat16 h = __float2bfloat16(f);
    return *reinterpret_cast<unsigned short*>(&h);
}

static __device__ inline f32x16 mfma_bf16(short8 a, short8 b, f32x16 c) {
    return __builtin_amdgcn_mfma_f32_32x32x16_bf16(a, b, c, 0, 0, 0);
}

// async global->LDS, 16B per lane; LDS dest = wave-uniform base + lane*16
#define GLL16(g, s) __builtin_amdgcn_global_load_lds( \
    (const __attribute__((address_space(1))) unsigned int*)(g), \
    (__attribute__((address_space(3))) unsigned int*)(s), 16, 0, 0)

// ---------------------------------------------------------------------------
// Weight conversion: wi' = bf16(wi * ln_w) (ln_w folded), wo' = bf16(wo).
// ---------------------------------------------------------------------------
__global__ __launch_bounds__(256)
void convert_weights(const float* __restrict__ wi, const float* __restrict__ wo,
                     const float* __restrict__ lnw,
                     unsigned short* __restrict__ wip, unsigned short* __restrict__ wop)
{
    const unsigned NWI = (unsigned)E * F * D;
    unsigned i4 = (blockIdx.x * 256u + threadIdx.x) * 4u;
    if (i4 < NWI) {
        float4 v = *(const float4*)(wi + i4);
        unsigned e = i4 / (unsigned)(F * D);
        unsigned d = i4 % (unsigned)D;
        float4 l = *(const float4*)(lnw + e * D + d);
        ushort4 o = { f2bf(v.x * l.x), f2bf(v.y * l.y), f2bf(v.z * l.z), f2bf(v.w * l.w) };
        *(ushort4*)(wip + i4) = o;
    } else {
        unsigned j = i4 - NWI;
        float4 v = *(const float4*)(wo + j);
        ushort4 o = { f2bf(v.x), f2bf(v.y), f2bf(v.z), f2bf(v.w) };
        *(ushort4*)(wop + j) = o;
    }
}

// ---------------------------------------------------------------------------
// Router + RMS-norm: logits (exact fp32), top-2, xn = bf16(x*rstd),
// out = wsum*x (residual term), per-token meta (sel, w01). NO atomics.
// ---------------------------------------------------------------------------
__global__ __launch_bounds__(256)
void router_norm_kernel(const float* __restrict__ x,
                        const float* __restrict__ rw,
                        float* __restrict__ logits,        // [T, E]
                        unsigned short* __restrict__ xn,   // [T, D] bf16
                        float* __restrict__ out,           // [T, D] <- wsum*x
                        int*   __restrict__ sel,           // [T] e0 | e1<<4
                        float2* __restrict__ w01)          // [T] (w0, w1)
{
    const int lane = threadIdx.x & 63;
    const int wid  = threadIdx.x >> 6;
    const int t = blockIdx.x * 4 + wid;
    if (t >= T) return;

    const float* xr = x + (size_t)t * D;
    float xv[12];
    float acc[8];
#pragma unroll
    for (int e = 0; e < 8; ++e) acc[e] = 0.f;
    float ssq = 0.f;
#pragma unroll
    for (int i = 0; i < 12; ++i) {
        const int k = lane + 64 * i;
        const float v = xr[k];
        xv[i] = v;
        ssq += v * v;
#pragma unroll
        for (int e = 0; e < 8; ++e) acc[e] += v * rw[e * D + k];
    }
#pragma unroll
    for (int off = 32; off; off >>= 1) {
        ssq += __shfl_xor(ssq, off);
#pragma unroll
        for (int e = 0; e < 8; ++e) acc[e] += __shfl_xor(acc[e], off);
    }

    int e0 = 0; float m0 = acc[0];
#pragma unroll
    for (int e = 1; e < 8; ++e) if (acc[e] > m0) { m0 = acc[e]; e0 = e; }
    int e1 = -1; float m1 = -3.4e38f;
#pragma unroll
    for (int e = 0; e < 8; ++e) if (e != e0 && acc[e] > m1) { m1 = acc[e]; e1 = e; }

    const float r  = expf(m1 - m0);
    const float w0 = 1.f / (1.f + r);
    const float w1 = r * w0;
    const float wsum = w0 + w1;
    const float rs = rsqrtf(ssq * (1.f / (float)D) + EPS);

    if (lane == 0) {
#pragma unroll
        for (int e = 0; e < 8; ++e) logits[t * 8 + e] = acc[e];
        sel[t] = e0 | (e1 << 4);
        w01[t] = make_float2(w0, w1);
    }

#pragma unroll
    for (int i = 0; i < 12; ++i) {
        const int k = lane + 64 * i;
        xn[(size_t)t * D + k] = f2bf(xv[i] * rs);
        out[(size_t)t * D + k] = wsum * xv[i];
    }
}

// ---------------------------------------------------------------------------
// List build: one block per expert, ballot/prefix compaction. Zero atomics.
// ---------------------------------------------------------------------------
__global__ __launch_bounds__(256)
void build_lists(const int* __restrict__ sel, const float2* __restrict__ w01,
                 int* __restrict__ counts, int* __restrict__ lists,
                 float* __restrict__ wlist)
{
    const int e = blockIdx.x;
    const int tid = threadIdx.x;
    const int lane = tid & 63;
    const int wv = tid >> 6;
    __shared__ int wtot[4];
    int cnt = 0;
    for (int c0 = 0; c0 < T; c0 += 256) {
        const int t = c0 + tid;
        const int s = sel[t];
        const bool m1 = ((s >> 4) & 15) == e;
        const bool m = ((s & 15) == e) || m1;
        const unsigned long long b = __ballot(m);
        const int pre = __popcll(b & ((1ULL << lane) - 1ULL));
        if (lane == 0) wtot[wv] = __popcll(b);
        __syncthreads();
        int wbase = 0;
#pragma unroll
        for (int i = 0; i < 4; ++i) if (i < wv) wbase += wtot[i];
        if (m) {
            const int pos = cnt + wbase + pre;
            lists[e * T + pos] = (t << 1) | (m1 ? 1 : 0);
            const float2 w = w01[t];
            wlist[e * T + pos] = m1 ? w.y : w.x;
        }
        cnt += wtot[0] + wtot[1] + wtot[2] + wtot[3];
        __syncthreads();
    }
    if (tid == 0) counts[e] = cnt;
}

// ---------------------------------------------------------------------------
// GEMM1: H[offs[e]+row][f] = relu( xn[tok(row)] . wip[e][half*FH+f] )
// m97 single-buffer structure: 128x128 tile, BK=64, 4 waves, 33 KB LDS ->
// 4 blocks/CU (16 waves) of TLP. XOR-swizzle: linear LDS dest +
// inverse-swizzled global source + swizzled ds_read.
// ---------------------------------------------------------------------------
__global__ __launch_bounds__(256)
void gemm1_kernel(const unsigned short* __restrict__ xn,
                  const unsigned short* __restrict__ wip,
                  const int* __restrict__ counts,
                  const int* __restrict__ lists,
                  unsigned short* __restrict__ H, int half)
{
    __shared__ unsigned short sA[128 * 64];
    __shared__ unsigned short sB[128 * 64];
    __shared__ int s_tok[128];

    const int bid = blockIdx.x;
    const int e  = bid & 7;
    const int mt = (bid >> 3) / 12;
    const int nt = (bid >> 3) % 12;
    const int cnt = counts[e];
    const int base = mt * 128;
    if (base >= cnt) return;
    int offe = 0;
    for (int i = 0; i < e; ++i) offe += counts[i];

    const int tid = threadIdx.x;
    const int w = tid >> 6, l = tid & 63;
    const int lo = l & 31, hi = l >> 5;
    const int wr = w >> 1, wc = w & 1;

    if (tid < 128) {
        const int idx = base + tid;
        s_tok[tid] = (idx < cnt) ? (lists[e * T + idx] >> 1) : 0;
    }
    __syncthreads();

    // inverse-swizzled global source chunk (16B units within each 128B span)
    const int r = (w * 4 + 0) * 8 + (l >> 3);          // row staged by j=0
    const int chS = ((l & 7) ^ ((l >> 3) & 7)) * 8;    // swizzled chunk, in shorts
    const unsigned short* aSrc[4];
    const unsigned short* bSrc[4];
#pragma unroll
    for (int j = 0; j < 4; ++j) {
        const int rj = r + j * 8;
        aSrc[j] = xn + (size_t)s_tok[rj] * D + chS;
        bSrc[j] = wip + ((size_t)e * F + half * FH + nt * 128 + rj) * D + chS;
    }
    char* sAc = (char*)sA;
    char* sBc = (char*)sB;

    f32x16 acc00, acc01, acc10, acc11;
#pragma unroll
    for (int q = 0; q < 16; ++q) { acc00[q] = 0.f; acc01[q] = 0.f; acc10[q] = 0.f; acc11[q] = 0.f; }

    const int rx = (lo & 7) << 4;                   // read-side row XOR
    const int arow0 = (wr * 64 + lo) * 128;
    const int arow1 = arow0 + 32 * 128;
    const int brow0 = (wc * 64 + lo) * 128;
    const int brow1 = brow0 + 32 * 128;

    for (int kt = 0; kt < 12; ++kt) {
        const int k0 = kt * 64;
#pragma unroll
        for (int j = 0; j < 4; ++j) {
            GLL16(aSrc[j] + k0, sAc + (w * 4 + j) * 1024);
            GLL16(bSrc[j] + k0, sBc + (w * 4 + j) * 1024);
        }
        __syncthreads();                 // stage complete (vmcnt drain) + rendezvous
#pragma unroll
        for (int ks = 0; ks < 4; ++ks) {
            const int coff = (hi * 16 + ks * 32) ^ rx;
            short8 a0 = *(const short8*)(sAc + arow0 + coff);
            short8 a1 = *(const short8*)(sAc + arow1 + coff);
            short8 b0 = *(const short8*)(sBc + brow0 + coff);
            short8 b1 = *(const short8*)(sBc + brow1 + coff);
            acc00 = mfma_bf16(a0, b0, acc00);
            acc01 = mfma_bf16(a0, b1, acc01);
            acc10 = mfma_bf16(a1, b0, acc10);
            acc11 = mfma_bf16(a1, b1, acc11);
        }
        __syncthreads();                 // all reads done before next stage
    }

    // epilogue: relu -> bf16 -> H  (rows >= cnt clamped; packed layout)
    const int cbase = nt * 128 + wc * 64 + lo;
#pragma unroll
    for (int rr = 0; rr < 16; ++rr) {
        const int crow = (rr & 3) + 8 * (rr >> 2) + 4 * hi;
        int lrow = wr * 64 + crow;
        if (base + lrow < cnt) {
            unsigned short* hp = H + (size_t)(offe + base + lrow) * FH + cbase;
            hp[0]  = f2bf(fmaxf(acc00[rr], 0.f));
            hp[32] = f2bf(fmaxf(acc01[rr], 0.f));
        }
        lrow += 32;
        if (base + lrow < cnt) {
            unsigned short* hp = H + (size_t)(offe + base + lrow) * FH + cbase;
            hp[0]  = f2bf(fmaxf(acc10[rr], 0.f));
            hp[32] = f2bf(fmaxf(acc11[rr], 0.f));
        }
    }
}

// ---------------------------------------------------------------------------
// GEMM2: ff[tok][d] (+)= w_tok * ( H[offs[e]+row] . wop[e][d][half*FH..] )
// Same single-buffer structure; K = 1536 per half.
// mode 0: atomicAdd into out (fallback, small ws)
// mode 1: ffout[slot][tok][d]  = w*acc   (plain store, h=0)
// mode 2: ffout[slot][tok][d] += w*acc   (load+add+store, h=1; stream-ordered)
// ---------------------------------------------------------------------------
__global__ __launch_bounds__(256)
void gemm2_kernel(const unsigned short* __restrict__ H,
                  const unsigned short* __restrict__ wop,
                  const int* __restrict__ counts,
                  const int* __restrict__ lists, const float* __restrict__ wlist,
                  float* __restrict__ out, float* __restrict__ ffout,
                  int half, int mode)
{
    __shared__ unsigned short sA[128 * 64];
    __shared__ unsigned short sB[128 * 64];
    __shared__ int   s_tok[128];
    __shared__ float s_wgt[128];

    const int bid = blockIdx.x;
    const int e  = bid & 7;
    const int mt = (bid >> 3) / 6;
    const int nt = (bid >> 3) % 6;
    const int cnt = counts[e];
    const int base = mt * 128;
    if (base >= cnt) return;
    int offe = 0;
    for (int i = 0; i < e; ++i) offe += counts[i];

    const int tid = threadIdx.x;
    const int w = tid >> 6, l = tid & 63;
    const int lo = l & 31, hi = l >> 5;
    const int wr = w >> 1, wc = w & 1;

    if (tid < 128) {
        const int idx = base + tid;
        const bool v = idx < cnt;
        s_tok[tid] = v ? lists[e * T + idx] : 0;
        s_wgt[tid] = v ? wlist[e * T + idx] : 0.f;
    }

    const int r = (w * 4 + 0) * 8 + (l >> 3);
    const int chS = ((l & 7) ^ ((l >> 3) & 7)) * 8;
    const unsigned short* aSrc[4];
    const unsigned short* bSrc[4];
#pragma unroll
    for (int j = 0; j < 4; ++j) {
        const int rj = r + j * 8;
        aSrc[j] = H + (size_t)(offe + base + rj) * FH + chS;
        bSrc[j] = wop + ((size_t)e * D + nt * 128 + rj) * F + half * FH + chS;
    }
    char* sAc = (char*)sA;
    char* sBc = (char*)sB;

    f32x16 acc00, acc01, acc10, acc11;
#pragma unroll
    for (int q = 0; q < 16; ++q) { acc00[q] = 0.f; acc01[q] = 0.f; acc10[q] = 0.f; acc11[q] = 0.f; }

    const int rx = (lo & 7) << 4;
    const int arow0 = (wr * 64 + lo) * 128;
    const int arow1 = arow0 + 32 * 128;
    const int brow0 = (wc * 64 + lo) * 128;
    const int brow1 = brow0 + 32 * 128;

    for (int kt = 0; kt < 24; ++kt) {
        const int k0 = kt * 64;
#pragma unroll
        for (int j = 0; j < 4; ++j) {
            GLL16(aSrc[j] + k0, sAc + (w * 4 + j) * 1024);
            GLL16(bSrc[j] + k0, sBc + (w * 4 + j) * 1024);
        }
        __syncthreads();
#pragma unroll
        for (int ks = 0; ks < 4; ++ks) {
            const int coff = (hi * 16 + ks * 32) ^ rx;
            short8 a0 = *(const short8*)(sAc + arow0 + coff);
            short8 a1 = *(const short8*)(sAc + arow1 + coff);
            short8 b0 = *(const short8*)(sBc + brow0 + coff);
            short8 b1 = *(const short8*)(sBc + brow1 + coff);
            acc00 = mfma_bf16(a0, b0, acc00);
            acc01 = mfma_bf16(a0, b1, acc01);
            acc10 = mfma_bf16(a1, b0, acc10);
            acc11 = mfma_bf16(a1, b1, acc11);
        }
        __syncthreads();
    }

    const int cbase = nt * 128 + wc * 64 + lo;
#pragma unroll
    for (int rr = 0; rr < 16; ++rr) {
        const int crow = (rr & 3) + 8 * (rr >> 2) + 4 * hi;
#pragma unroll
        for (int mh = 0; mh < 2; ++mh) {
            const int lrow = wr * 64 + crow + mh * 32;
            if (base + lrow < cnt) {
                const int pk = s_tok[lrow];
                const float wgt = s_wgt[lrow];
                const float v0 = wgt * (mh ? acc10[rr] : acc00[rr]);
                const float v1 = wgt * (mh ? acc11[rr] : acc01[rr]);
                if (mode == 0) {
                    float* dst = out + (size_t)(pk >> 1) * D + cbase;
                    atomicAdd(dst,      v0);
                    atomicAdd(dst + 32, v1);
                } else {
                    float* dst = ffout + ((size_t)(pk & 1) * T + (pk >> 1)) * D + cbase;
                    if (mode == 1) { dst[0] = v0;  dst[32] = v1; }
                    else           { dst[0] += v0; dst[32] += v1; }
                }
            }
        }
    }
}

// ---------------------------------------------------------------------------
// Combine (ffout mode only): out (= wsum*x) += ffout[0] + ffout[1]
// ---------------------------------------------------------------------------
__global__ __launch_bounds__(256)
void combine_kernel(const float* __restrict__ ffout, float* __restrict__ out)
{
    const long long i4 = ((long long)blockIdx.x * 256 + threadIdx.x) * 4;
    float4 o  = *(const float4*)(out + i4);
    float4 f0 = *(const float4*)(ffout + i4);
    float4 f1 = *(const float4*)(ffout + (long long)T * D + i4);
    o.x += f0.x + f1.x; o.y += f0.y + f1.y;
    o.z += f0.z + f1.z; o.w += f0.w + f1.w;
    *(float4*)(out + i4) = o;
}

// ---------------------------------------------------------------------------
extern "C" void kernel_launch(void* const* d_in, const int* in_sizes, int n_in,
                              void* d_out, int out_size, void* d_ws, size_t ws_size,
                              hipStream_t stream) {
    const float* x   = (const float*)d_in[0];   // [T, D]
    const float* rw  = (const float*)d_in[1];   // [E, D]
    const float* lnw = (const float*)d_in[2];   // [E, D]
    const float* wi  = (const float*)d_in[3];   // [E, F, D]
    const float* wo  = (const float*)d_in[4];   // [E, D, F]

    float* out    = (float*)d_out;                    // [T, D]
    float* logits = (float*)d_out + (size_t)T * D;    // [T, E]

    char* ws = (char*)d_ws;
    int*            counts = (int*)(ws);                       // 64 B
    int*            sel    = (int*)(ws + 4096);                // 32 KB
    float2*         w01    = (float2*)(ws + 65536);            // 64 KB
    int*            lists  = (int*)(ws + 131072);              // 256 KB
    float*          wlist  = (float*)(ws + 393216);            // 256 KB
    unsigned short* xn     = (unsigned short*)(ws + 1048576);  // 12.6 MB
    unsigned short* wip    = (unsigned short*)(ws + 13631488); // 37.7 MB
    unsigned short* wop    = (unsigned short*)(ws + 51380224); // 37.7 MB
    unsigned short* H      = (unsigned short*)(ws + 89128960); // 51.1 MB (ends 140247040)
    float*          ffout  = (float*)(ws + 140247040);         // 50.3 MB (optional)

    // ffout path needs 190.6 MB of ws; ws_size is fixed per deployment, so
    // this branch is deterministic across calls.
    const bool big = ws_size >= 190578688ULL;

    convert_weights<<<36864, 256, 0, stream>>>(wi, wo, lnw, wip, wop);

    router_norm_kernel<<<T / 4, 256, 0, stream>>>(x, rw, logits, xn, out,
                                                  sel, w01);

    build_lists<<<E, 256, 0, stream>>>(sel, w01, counts, lists, wlist);

    for (int h = 0; h < 2; ++h) {
        // worst-case grid (cap 4096 rows/expert); blocks early-exit past cnt
        gemm1_kernel<<<32 * 12 * 8, 256, 0, stream>>>(xn, wip, counts,
                                                      lists, H, h);
        const int mode = big ? (h ? 2 : 1) : 0;
        gemm2_kernel<<<32 * 6 * 8, 256, 0, stream>>>(H, wop, counts,
                                                     lists, wlist, out,
                                                     ffout, h, mode);
    }

    if (big) combine_kernel<<<T * D / 4 / 256, 256, 0, stream>>>(ffout, out);
}

// Round 7
// 360.122 us; speedup vs baseline: 71.1566x; 1.0106x over previous
//
#include <hip/hip_runtime.h>
#include <hip/hip_bf16.h>
#include <math.h>

typedef short short8 __attribute__((ext_vector_type(8)));
typedef float f32x16 __attribute__((ext_vector_type(16)));

constexpr int D = 768;    // model dim
constexpr int E = 8;      // experts
constexpr int F = 3072;   // ffn dim
constexpr int FH = 1536;  // F half
constexpr int T = 8192;   // tokens
constexpr float EPS = 1e-6f;

static __device__ inline unsigned short f2bf(float f) {
    __hip_bfloat16 h = __float2bfloat16(f);
    return *reinterpret_cast<unsigned short*>(&h);
}

static __device__ inline f32x16 mfma_bf16(short8 a, short8 b, f32x16 c) {
    return __builtin_amdgcn_mfma_f32_32x32x16_bf16(a, b, c, 0, 0, 0);
}

// async global->LDS, 16B per lane; LDS dest = wave-uniform base + lane*16
#define GLL16(g, s) __builtin_amdgcn_global_load_lds( \
    (const __attribute__((address_space(1))) unsigned int*)(g), \
    (__attribute__((address_space(3))) unsigned int*)(s), 16, 0, 0)

// ---------------------------------------------------------------------------
// Weight conversion: wi' = bf16(wi * ln_w) (ln_w folded), wo' = bf16(wo).
// ---------------------------------------------------------------------------
__global__ __launch_bounds__(256)
void convert_weights(const float* __restrict__ wi, const float* __restrict__ wo,
                     const float* __restrict__ lnw,
                     unsigned short* __restrict__ wip, unsigned short* __restrict__ wop)
{
    const unsigned NWI = (unsigned)E * F * D;
    unsigned i4 = (blockIdx.x * 256u + threadIdx.x) * 4u;
    if (i4 < NWI) {
        float4 v = *(const float4*)(wi + i4);
        unsigned e = i4 / (unsigned)(F * D);
        unsigned d = i4 % (unsigned)D;
        float4 l = *(const float4*)(lnw + e * D + d);
        ushort4 o = { f2bf(v.x * l.x), f2bf(v.y * l.y), f2bf(v.z * l.z), f2bf(v.w * l.w) };
        *(ushort4*)(wip + i4) = o;
    } else {
        unsigned j = i4 - NWI;
        float4 v = *(const float4*)(wo + j);
        ushort4 o = { f2bf(v.x), f2bf(v.y), f2bf(v.z), f2bf(v.w) };
        *(ushort4*)(wop + j) = o;
    }
}

// ---------------------------------------------------------------------------
// Router + RMS-norm: logits (exact fp32), top-2, xn = bf16(x*rstd),
// out = wsum*x (residual term), per-token meta (sel, w01). NO atomics.
// ---------------------------------------------------------------------------
__global__ __launch_bounds__(256)
void router_norm_kernel(const float* __restrict__ x,
                        const float* __restrict__ rw,
                        float* __restrict__ logits,        // [T, E]
                        unsigned short* __restrict__ xn,   // [T, D] bf16
                        float* __restrict__ out,           // [T, D] <- wsum*x
                        int*   __restrict__ sel,           // [T] e0 | e1<<4
                        float2* __restrict__ w01)          // [T] (w0, w1)
{
    const int lane = threadIdx.x & 63;
    const int wid  = threadIdx.x >> 6;
    const int t = blockIdx.x * 4 + wid;
    if (t >= T) return;

    const float* xr = x + (size_t)t * D;
    float xv[12];
    float acc[8];
#pragma unroll
    for (int e = 0; e < 8; ++e) acc[e] = 0.f;
    float ssq = 0.f;
#pragma unroll
    for (int i = 0; i < 12; ++i) {
        const int k = lane + 64 * i;
        const float v = xr[k];
        xv[i] = v;
        ssq += v * v;
#pragma unroll
        for (int e = 0; e < 8; ++e) acc[e] += v * rw[e * D + k];
    }
#pragma unroll
    for (int off = 32; off; off >>= 1) {
        ssq += __shfl_xor(ssq, off);
#pragma unroll
        for (int e = 0; e < 8; ++e) acc[e] += __shfl_xor(acc[e], off);
    }

    int e0 = 0; float m0 = acc[0];
#pragma unroll
    for (int e = 1; e < 8; ++e) if (acc[e] > m0) { m0 = acc[e]; e0 = e; }
    int e1 = -1; float m1 = -3.4e38f;
#pragma unroll
    for (int e = 0; e < 8; ++e) if (e != e0 && acc[e] > m1) { m1 = acc[e]; e1 = e; }

    const float r  = expf(m1 - m0);
    const float w0 = 1.f / (1.f + r);
    const float w1 = r * w0;
    const float wsum = w0 + w1;
    const float rs = rsqrtf(ssq * (1.f / (float)D) + EPS);

    if (lane == 0) {
#pragma unroll
        for (int e = 0; e < 8; ++e) logits[t * 8 + e] = acc[e];
        sel[t] = e0 | (e1 << 4);
        w01[t] = make_float2(w0, w1);
    }

#pragma unroll
    for (int i = 0; i < 12; ++i) {
        const int k = lane + 64 * i;
        xn[(size_t)t * D + k] = f2bf(xv[i] * rs);
        out[(size_t)t * D + k] = wsum * xv[i];
    }
}

// ---------------------------------------------------------------------------
// List build: one block per expert, ballot/prefix compaction. Zero atomics.
// ---------------------------------------------------------------------------
__global__ __launch_bounds__(256)
void build_lists(const int* __restrict__ sel, const float2* __restrict__ w01,
                 int* __restrict__ counts, int* __restrict__ lists,
                 float* __restrict__ wlist)
{
    const int e = blockIdx.x;
    const int tid = threadIdx.x;
    const int lane = tid & 63;
    const int wv = tid >> 6;
    __shared__ int wtot[4];
    int cnt = 0;
    for (int c0 = 0; c0 < T; c0 += 256) {
        const int t = c0 + tid;
        const int s = sel[t];
        const bool m1 = ((s >> 4) & 15) == e;
        const bool m = ((s & 15) == e) || m1;
        const unsigned long long b = __ballot(m);
        const int pre = __popcll(b & ((1ULL << lane) - 1ULL));
        if (lane == 0) wtot[wv] = __popcll(b);
        __syncthreads();
        int wbase = 0;
#pragma unroll
        for (int i = 0; i < 4; ++i) if (i < wv) wbase += wtot[i];
        if (m) {
            const int pos = cnt + wbase + pre;
            lists[e * T + pos] = (t << 1) | (m1 ? 1 : 0);
            const float2 w = w01[t];
            wlist[e * T + pos] = m1 ? w.y : w.x;
        }
        cnt += wtot[0] + wtot[1] + wtot[2] + wtot[3];
        __syncthreads();
    }
    if (tid == 0) counts[e] = cnt;
}

// ===========================================================================
// Counted-vmcnt 2-deep pipelined GEMM core (T3 minimum + T4), 128x128 tile,
// BK=64, 4 waves, 32x32x16 bf16 MFMA, XOR-swizzled LDS (linear dest +
// inverse-swizzled global src + swizzled ds_read).
// Per kt: ds_read 16 frags -> lgkmcnt(0)+schedbar -> s_barrier (WAR safe) ->
// STAGE kt+2 into freed buffer -> MFMA -> vmcnt(8) (= next tile landed,
// newest 8 loads stay in flight) -> s_barrier.
// ===========================================================================

#define GEMM_PIPE_LOOP(NKT)                                                   \
    /* prologue: stage k0 -> buf0, k1 -> buf1 (16 loads outstanding) */       \
    _Pragma("unroll")                                                         \
    for (int j = 0; j < 4; ++j) {                                             \
        GLL16(aSrc[j], smem + stg + j * 1024);                                \
        GLL16(bSrc[j], smem + 16384 + stg + j * 1024);                        \
    }                                                                         \
    _Pragma("unroll")                                                         \
    for (int j = 0; j < 4; ++j) {                                             \
        GLL16(aSrc[j] + 64, smem + 32768 + stg + j * 1024);                   \
        GLL16(bSrc[j] + 64, smem + 32768 + 16384 + stg + j * 1024);           \
    }                                                                         \
    asm volatile("s_waitcnt vmcnt(8)" ::: "memory");                          \
    __builtin_amdgcn_s_barrier();                                             \
    int cur = 0;                                                              \
    for (int kt = 0; kt < (NKT); ++kt) {                                      \
        const char* cA = smem + cur * 32768;                                  \
        const char* cB = cA + 16384;                                          \
        short8 fA0[4], fA1[4], fB0[4], fB1[4];                                \
        _Pragma("unroll")                                                     \
        for (int ks = 0; ks < 4; ++ks) {                                      \
            const int coff = (hi * 16 + ks * 32) ^ rx;                        \
            fA0[ks] = *(const short8*)(cA + arow0 + coff);                    \
            fA1[ks] = *(const short8*)(cA + arow1 + coff);                    \
            fB0[ks] = *(const short8*)(cB + brow0 + coff);                    \
            fB1[ks] = *(const short8*)(cB + brow1 + coff);                    \
        }                                                                     \
        asm volatile("s_waitcnt lgkmcnt(0)" ::: "memory");                    \
        __builtin_amdgcn_sched_barrier(0);                                    \
        __builtin_amdgcn_s_barrier();  /* all waves done reading buf[cur] */  \
        {                                                                     \
            const int kn = (kt + 2 < (NKT) ? kt + 2 : (NKT)-1) * 64;          \
            char* dA = smem + cur * 32768;                                    \
            _Pragma("unroll")                                                 \
            for (int j = 0; j < 4; ++j) {                                     \
                GLL16(aSrc[j] + kn, dA + stg + j * 1024);                     \
                GLL16(bSrc[j] + kn, dA + 16384 + stg + j * 1024);             \
            }                                                                 \
        }                                                                     \
        __builtin_amdgcn_sched_barrier(0);                                    \
        _Pragma("unroll")                                                     \
        for (int ks = 0; ks < 4; ++ks) {                                      \
            acc00 = mfma_bf16(fA0[ks], fB0[ks], acc00);                       \
            acc01 = mfma_bf16(fA0[ks], fB1[ks], acc01);                       \
            acc10 = mfma_bf16(fA1[ks], fB0[ks], acc10);                       \
            acc11 = mfma_bf16(fA1[ks], fB1[ks], acc11);                       \
        }                                                                     \
        asm volatile("s_waitcnt vmcnt(8)" ::: "memory");                      \
        __builtin_amdgcn_s_barrier();  /* next tile present in buf[cur^1] */  \
        cur ^= 1;                                                             \
    }

// ---------------------------------------------------------------------------
// GEMM1: H[offs[e]+row][f] = relu( xn[tok(row)] . wip[e][half*FH+f] )
// ---------------------------------------------------------------------------
__global__ __launch_bounds__(256)
void gemm1_kernel(const unsigned short* __restrict__ xn,
                  const unsigned short* __restrict__ wip,
                  const int* __restrict__ counts,
                  const int* __restrict__ lists,
                  unsigned short* __restrict__ H, int half)
{
    __shared__ __align__(16) char smem[65536];   // 2 x (sA 16K + sB 16K)
    __shared__ int s_tok[128];

    const int bid = blockIdx.x;
    const int e  = bid & 7;
    const int mt = (bid >> 3) / 12;
    const int nt = (bid >> 3) % 12;
    const int cnt = counts[e];
    const int base = mt * 128;
    if (base >= cnt) return;
    int offe = 0;
    for (int i = 0; i < e; ++i) offe += counts[i];

    const int tid = threadIdx.x;
    const int w = tid >> 6, l = tid & 63;
    const int lo = l & 31, hi = l >> 5;
    const int wr = w >> 1, wc = w & 1;

    if (tid < 128) {
        const int idx = base + tid;
        s_tok[tid] = (idx < cnt) ? (lists[e * T + idx] >> 1) : 0;
    }
    __syncthreads();

    // inverse-swizzled global source chunk (16B units within each 128B span)
    const int r = (w * 4 + 0) * 8 + (l >> 3);          // row staged by j=0
    const int chS = ((l & 7) ^ ((l >> 3) & 7)) * 8;    // swizzled chunk, in shorts
    const unsigned short* aSrc[4];
    const unsigned short* bSrc[4];
#pragma unroll
    for (int j = 0; j < 4; ++j) {
        const int rj = r + j * 8;
        aSrc[j] = xn + (size_t)s_tok[rj] * D + chS;
        bSrc[j] = wip + ((size_t)e * F + half * FH + nt * 128 + rj) * D + chS;
    }

    f32x16 acc00, acc01, acc10, acc11;
#pragma unroll
    for (int q = 0; q < 16; ++q) { acc00[q] = 0.f; acc01[q] = 0.f; acc10[q] = 0.f; acc11[q] = 0.f; }

    const int rx = (lo & 7) << 4;                   // read-side row XOR
    const int arow0 = (wr * 64 + lo) * 128;
    const int arow1 = arow0 + 32 * 128;
    const int brow0 = (wc * 64 + lo) * 128;
    const int brow1 = brow0 + 32 * 128;
    const int stg = w * 4096;

    GEMM_PIPE_LOOP(12)

    // epilogue: relu -> bf16 -> H  (rows >= cnt clamped; packed layout)
    const int cbase = nt * 128 + wc * 64 + lo;
#pragma unroll
    for (int rr = 0; rr < 16; ++rr) {
        const int crow = (rr & 3) + 8 * (rr >> 2) + 4 * hi;
        int lrow = wr * 64 + crow;
        if (base + lrow < cnt) {
            unsigned short* hp = H + (size_t)(offe + base + lrow) * FH + cbase;
            hp[0]  = f2bf(fmaxf(acc00[rr], 0.f));
            hp[32] = f2bf(fmaxf(acc01[rr], 0.f));
        }
        lrow += 32;
        if (base + lrow < cnt) {
            unsigned short* hp = H + (size_t)(offe + base + lrow) * FH + cbase;
            hp[0]  = f2bf(fmaxf(acc10[rr], 0.f));
            hp[32] = f2bf(fmaxf(acc11[rr], 0.f));
        }
    }
}

// ---------------------------------------------------------------------------
// GEMM2: ff[tok][d] (+)= w_tok * ( H[offs[e]+row] . wop[e][d][half*FH..] )
// mode 0: atomicAdd into out (fallback, small ws)
// mode 1: ffout[slot][tok][d]  = w*acc   (plain store, h=0)
// mode 2: ffout[slot][tok][d] += w*acc   (load+add+store, h=1; stream-ordered)
// ---------------------------------------------------------------------------
__global__ __launch_bounds__(256)
void gemm2_kernel(const unsigned short* __restrict__ H,
                  const unsigned short* __restrict__ wop,
                  const int* __restrict__ counts,
                  const int* __restrict__ lists, const float* __restrict__ wlist,
                  float* __restrict__ out, float* __restrict__ ffout,
                  int half, int mode)
{
    __shared__ __align__(16) char smem[65536];
    __shared__ int   s_tok[128];
    __shared__ float s_wgt[128];

    const int bid = blockIdx.x;
    const int e  = bid & 7;
    const int mt = (bid >> 3) / 6;
    const int nt = (bid >> 3) % 6;
    const int cnt = counts[e];
    const int base = mt * 128;
    if (base >= cnt) return;
    int offe = 0;
    for (int i = 0; i < e; ++i) offe += counts[i];

    const int tid = threadIdx.x;
    const int w = tid >> 6, l = tid & 63;
    const int lo = l & 31, hi = l >> 5;
    const int wr = w >> 1, wc = w & 1;

    if (tid < 128) {
        const int idx = base + tid;
        const bool v = idx < cnt;
        s_tok[tid] = v ? lists[e * T + idx] : 0;
        s_wgt[tid] = v ? wlist[e * T + idx] : 0.f;
    }
    __syncthreads();   // s_tok is read cross-wave below (race fix)

    const int r = (w * 4 + 0) * 8 + (l >> 3);
    const int chS = ((l & 7) ^ ((l >> 3) & 7)) * 8;
    const unsigned short* aSrc[4];
    const unsigned short* bSrc[4];
#pragma unroll
    for (int j = 0; j < 4; ++j) {
        const int rj = r + j * 8;
        aSrc[j] = H + (size_t)(offe + base + rj) * FH + chS;
        bSrc[j] = wop + ((size_t)e * D + nt * 128 + rj) * F + half * FH + chS;
    }

    f32x16 acc00, acc01, acc10, acc11;
#pragma unroll
    for (int q = 0; q < 16; ++q) { acc00[q] = 0.f; acc01[q] = 0.f; acc10[q] = 0.f; acc11[q] = 0.f; }

    const int rx = (lo & 7) << 4;
    const int arow0 = (wr * 64 + lo) * 128;
    const int arow1 = arow0 + 32 * 128;
    const int brow0 = (wc * 64 + lo) * 128;
    const int brow1 = brow0 + 32 * 128;
    const int stg = w * 4096;

    GEMM_PIPE_LOOP(24)

    const int cbase = nt * 128 + wc * 64 + lo;
#pragma unroll
    for (int rr = 0; rr < 16; ++rr) {
        const int crow = (rr & 3) + 8 * (rr >> 2) + 4 * hi;
#pragma unroll
        for (int mh = 0; mh < 2; ++mh) {
            const int lrow = wr * 64 + crow + mh * 32;
            if (base + lrow < cnt) {
                const int pk = s_tok[lrow];
                const float wgt = s_wgt[lrow];
                const float v0 = wgt * (mh ? acc10[rr] : acc00[rr]);
                const float v1 = wgt * (mh ? acc11[rr] : acc01[rr]);
                if (mode == 0) {
                    float* dst = out + (size_t)(pk >> 1) * D + cbase;
                    atomicAdd(dst,      v0);
                    atomicAdd(dst + 32, v1);
                } else {
                    float* dst = ffout + ((size_t)(pk & 1) * T + (pk >> 1)) * D + cbase;
                    if (mode == 1) { dst[0] = v0;  dst[32] = v1; }
                    else           { dst[0] += v0; dst[32] += v1; }
                }
            }
        }
    }
}

// ---------------------------------------------------------------------------
// Combine (ffout mode only): out (= wsum*x) += ffout[0] + ffout[1]
// ---------------------------------------------------------------------------
__global__ __launch_bounds__(256)
void combine_kernel(const float* __restrict__ ffout, float* __restrict__ out)
{
    const long long i4 = ((long long)blockIdx.x * 256 + threadIdx.x) * 4;
    float4 o  = *(const float4*)(out + i4);
    float4 f0 = *(const float4*)(ffout + i4);
    float4 f1 = *(const float4*)(ffout + (long long)T * D + i4);
    o.x += f0.x + f1.x; o.y += f0.y + f1.y;
    o.z += f0.z + f1.z; o.w += f0.w + f1.w;
    *(float4*)(out + i4) = o;
}

// ---------------------------------------------------------------------------
extern "C" void kernel_launch(void* const* d_in, const int* in_sizes, int n_in,
                              void* d_out, int out_size, void* d_ws, size_t ws_size,
                              hipStream_t stream) {
    const float* x   = (const float*)d_in[0];   // [T, D]
    const float* rw  = (const float*)d_in[1];   // [E, D]
    const float* lnw = (const float*)d_in[2];   // [E, D]
    const float* wi  = (const float*)d_in[3];   // [E, F, D]
    const float* wo  = (const float*)d_in[4];   // [E, D, F]

    float* out    = (float*)d_out;                    // [T, D]
    float* logits = (float*)d_out + (size_t)T * D;    // [T, E]

    char* ws = (char*)d_ws;
    int*            counts = (int*)(ws);                       // 64 B
    int*            sel    = (int*)(ws + 4096);                // 32 KB
    float2*         w01    = (float2*)(ws + 65536);            // 64 KB
    int*            lists  = (int*)(ws + 131072);              // 256 KB
    float*          wlist  = (float*)(ws + 393216);            // 256 KB
    unsigned short* xn     = (unsigned short*)(ws + 1048576);  // 12.6 MB
    unsigned short* wip    = (unsigned short*)(ws + 13631488); // 37.7 MB
    unsigned short* wop    = (unsigned short*)(ws + 51380224); // 37.7 MB
    unsigned short* H      = (unsigned short*)(ws + 89128960); // 51.1 MB (ends 140247040)
    float*          ffout  = (float*)(ws + 140247040);         // 50.3 MB (optional)

    // ffout path needs 190.6 MB of ws; ws_size is fixed per deployment, so
    // this branch is deterministic across calls.
    const bool big = ws_size >= 190578688ULL;

    convert_weights<<<36864, 256, 0, stream>>>(wi, wo, lnw, wip, wop);

    router_norm_kernel<<<T / 4, 256, 0, stream>>>(x, rw, logits, xn, out,
                                                  sel, w01);

    build_lists<<<E, 256, 0, stream>>>(sel, w01, counts, lists, wlist);

    for (int h = 0; h < 2; ++h) {
        // worst-case grid (cap 4096 rows/expert); blocks early-exit past cnt
        gemm1_kernel<<<32 * 12 * 8, 256, 0, stream>>>(xn, wip, counts,
                                                      lists, H, h);
        const int mode = big ? (h ? 2 : 1) : 0;
        gemm2_kernel<<<32 * 6 * 8, 256, 0, stream>>>(H, wop, counts,
                                                     lists, wlist, out,
                                                     ffout, h, mode);
    }

    if (big) combine_kernel<<<T * D / 4 / 256, 256, 0, stream>>>(ffout, out);
}